// Round 1
// baseline (2275.747 us; speedup 1.0000x reference)
//
#include <hip/hip_runtime.h>
#include <hip/hip_bf16.h>

// Problem constants
#define BSZ 16
#define LP 128
#define LR 1024
#define DD 128
#define DG 640
#define KH 7

// ---------------------------------------------------------------------------
// Light encoder kernel: embeddings (3 x 128 cols) + small dense matmul (128)
// enc layout: [BL, 640] row-major. Writes cols 0..511. Col 512..639 written by
// the pretrain GEMM.
// ---------------------------------------------------------------------------
__global__ __launch_bounds__(128) void encoder_light(
    const int* __restrict__ xs, const int* __restrict__ xss,
    const int* __restrict__ x2, const float* __restrict__ xd, int Kd,
    const float* __restrict__ Eseq, const float* __restrict__ Ess,
    const float* __restrict__ Etwo,
    const float* __restrict__ Wd, const float* __restrict__ bd,
    const float* __restrict__ mask, float* __restrict__ enc) {
  int row = blockIdx.x;
  int t = threadIdx.x;
  float m = mask[row];
  int i0 = xs[row], i1 = xss[row], i2 = x2[row];
  float* e = enc + (size_t)row * DG;
  e[t]       = Eseq[i0 * DD + t] * m;
  e[DD + t]  = Ess[i1 * DD + t] * m;
  e[2*DD + t]= Etwo[i2 * DD + t] * m;
  float acc = bd[t];
  const float* xr = xd + (size_t)row * Kd;
  for (int i = 0; i < Kd; ++i) acc = fmaf(xr[i], Wd[i * DD + t], acc);
  e[3*DD + t] = acc * m;
}

// ---------------------------------------------------------------------------
// Column-degree -> dinv kernel. deg[b,c] = sum_r (adj[b,r,c]!=0 || r==c)
// ---------------------------------------------------------------------------
__global__ __launch_bounds__(128) void degree_k(
    const float* __restrict__ adj, float* __restrict__ dinv, int L) {
  int b = blockIdx.y;
  int c = blockIdx.x * 128 + threadIdx.x;
  if (c >= L) return;
  const float* adjB = adj + (size_t)b * L * L;
  float deg = 0.f;
  for (int r = 0; r < L; ++r) {
    float a = adjB[(size_t)r * L + c];
    deg += (a != 0.f || r == c) ? 1.f : 0.f;
  }
  dinv[b * L + c] = rsqrtf(deg);
}

// ---------------------------------------------------------------------------
// Generic tiled GEMM (NN): C[m,n] = sum_k A[m,k]*B[k,n]
// epilogue: v = acc*rowscale[m] + bias[n]; (relu); v *= rowmask[m]
// 64x64 tile, BK=16, 256 threads, 4x4 per thread.
// ---------------------------------------------------------------------------
__global__ __launch_bounds__(256) void gemm_nn(
    const float* __restrict__ A, int lda, const float* __restrict__ B, int ldb,
    float* __restrict__ C, int ldc, int M, int N, int K,
    const float* __restrict__ bias, const float* __restrict__ rowscale,
    const float* __restrict__ rowmask, int relu) {
  __shared__ float As[16][68];
  __shared__ float Bs[16][68];
  int tid = threadIdx.x;
  int tx = tid & 15, ty = tid >> 4;
  int m0 = blockIdx.y * 64, n0 = blockIdx.x * 64;
  float acc[4][4] = {};
  for (int k0 = 0; k0 < K; k0 += 16) {
    #pragma unroll
    for (int s = 0; s < 4; ++s) {
      int idx = tid + s * 256;
      int kk = idx & 15, mm = idx >> 4;
      As[kk][mm] = A[(size_t)(m0 + mm) * lda + k0 + kk];
    }
    #pragma unroll
    for (int s = 0; s < 4; ++s) {
      int idx = tid + s * 256;
      int nn = idx & 63, kk = idx >> 6;
      Bs[kk][nn] = B[(size_t)(k0 + kk) * ldb + n0 + nn];
    }
    __syncthreads();
    #pragma unroll
    for (int kk = 0; kk < 16; ++kk) {
      float a[4], b[4];
      #pragma unroll
      for (int i = 0; i < 4; ++i) a[i] = As[kk][ty * 4 + i];
      #pragma unroll
      for (int j = 0; j < 4; ++j) b[j] = Bs[kk][tx * 4 + j];
      #pragma unroll
      for (int i = 0; i < 4; ++i)
        #pragma unroll
        for (int j = 0; j < 4; ++j) acc[i][j] = fmaf(a[i], b[j], acc[i][j]);
    }
    __syncthreads();
  }
  #pragma unroll
  for (int i = 0; i < 4; ++i) {
    int m = m0 + ty * 4 + i;
    float rs = rowscale ? rowscale[m] : 1.f;
    float rm = rowmask ? rowmask[m] : 1.f;
    #pragma unroll
    for (int j = 0; j < 4; ++j) {
      int n = n0 + tx * 4 + j;
      float v = acc[i][j] * rs;
      if (bias) v += bias[n];
      if (relu) v = fmaxf(v, 0.f);
      v *= rm;
      C[(size_t)m * ldc + n] = v;
    }
  }
}

// ---------------------------------------------------------------------------
// Aggregation GEMM (TN, batched over z=b):
// Y[b,c,d] = relu( dinv[b,c] * sum_r Ahat[b,r,c]*X[b,r,d] + bias[d] (+E) ) * mask
// X rows already pre-scaled by dinv[r] (done in gemm_nn epilogue).
// ---------------------------------------------------------------------------
__global__ __launch_bounds__(256) void gemm_agg(
    const float* __restrict__ adj, const float* __restrict__ X,
    const float* __restrict__ dinv, const float* __restrict__ bias,
    const float* __restrict__ addE, const float* __restrict__ rowmask,
    float* __restrict__ Y, int L) {
  int b = blockIdx.z;
  __shared__ float As[16][68];  // [r][c]
  __shared__ float Bs[16][68];  // [r][d]
  int tid = threadIdx.x;
  int tx = tid & 15, ty = tid >> 4;
  int c0 = blockIdx.y * 64, d0 = blockIdx.x * 64;
  const float* adjB = adj + (size_t)b * L * L;
  const float* XB = X + (size_t)b * L * DG;
  float acc[4][4] = {};
  for (int r0 = 0; r0 < L; r0 += 16) {
    #pragma unroll
    for (int s = 0; s < 4; ++s) {
      int idx = tid + s * 256;
      int mm = idx & 63, kk = idx >> 6;
      int r = r0 + kk, c = c0 + mm;
      float a = adjB[(size_t)r * L + c];
      As[kk][mm] = (a != 0.f || r == c) ? 1.f : 0.f;
    }
    #pragma unroll
    for (int s = 0; s < 4; ++s) {
      int idx = tid + s * 256;
      int nn = idx & 63, kk = idx >> 6;
      Bs[kk][nn] = XB[(size_t)(r0 + kk) * DG + d0 + nn];
    }
    __syncthreads();
    #pragma unroll
    for (int kk = 0; kk < 16; ++kk) {
      float a[4], b2[4];
      #pragma unroll
      for (int i = 0; i < 4; ++i) a[i] = As[kk][ty * 4 + i];
      #pragma unroll
      for (int j = 0; j < 4; ++j) b2[j] = Bs[kk][tx * 4 + j];
      #pragma unroll
      for (int i = 0; i < 4; ++i)
        #pragma unroll
        for (int j = 0; j < 4; ++j) acc[i][j] = fmaf(a[i], b2[j], acc[i][j]);
    }
    __syncthreads();
  }
  #pragma unroll
  for (int i = 0; i < 4; ++i) {
    int c = c0 + ty * 4 + i;
    float di = dinv[b * L + c];
    float rm = rowmask ? rowmask[b * L + c] : 1.f;
    #pragma unroll
    for (int j = 0; j < 4; ++j) {
      int d = d0 + tx * 4 + j;
      float v = acc[i][j] * di + bias[d];
      if (addE) v += addE[((size_t)(b * L + c)) * DG + d];
      v = fmaxf(v, 0.f);
      v *= rm;
      Y[((size_t)(b * L + c)) * DG + d] = v;
    }
  }
}

// ---------------------------------------------------------------------------
// FC-trans GEMM (batched over z = kh*B + b). M-dim = o (128), N-dim = l (L),
// K = 640: C[o,l] = relu( sum_d Wt[kh,o,d]*f[b,l,d] + bt[kh,o] )
// Written to out[((kh*B+b)*128 + o)*L + l] -> coalesced along l.
// ---------------------------------------------------------------------------
__global__ __launch_bounds__(256) void gemm_fct(
    const float* __restrict__ Wt, const float* __restrict__ bt,
    const float* __restrict__ f, float* __restrict__ out, int L) {
  int z = blockIdx.z;
  int kh = z / BSZ, b = z % BSZ;
  __shared__ float As[16][68];  // [d][o]
  __shared__ float Bs[16][68];  // [d][l]
  int tid = threadIdx.x;
  int tx = tid & 15, ty = tid >> 4;
  int o0 = blockIdx.y * 64, l0 = blockIdx.x * 64;
  const float* Wk = Wt + (size_t)kh * DD * DG;
  const float* fB = f + (size_t)b * L * DG;
  float acc[4][4] = {};
  for (int k0 = 0; k0 < DG; k0 += 16) {
    #pragma unroll
    for (int s = 0; s < 4; ++s) {
      int idx = tid + s * 256;
      int kk = idx & 15, mm = idx >> 4;
      As[kk][mm] = Wk[(size_t)(o0 + mm) * DG + k0 + kk];
    }
    #pragma unroll
    for (int s = 0; s < 4; ++s) {
      int idx = tid + s * 256;
      int kk = idx & 15, nn = idx >> 4;
      Bs[kk][nn] = fB[(size_t)(l0 + nn) * DG + k0 + kk];
    }
    __syncthreads();
    #pragma unroll
    for (int kk = 0; kk < 16; ++kk) {
      float a[4], b2[4];
      #pragma unroll
      for (int i = 0; i < 4; ++i) a[i] = As[kk][ty * 4 + i];
      #pragma unroll
      for (int j = 0; j < 4; ++j) b2[j] = Bs[kk][tx * 4 + j];
      #pragma unroll
      for (int i = 0; i < 4; ++i)
        #pragma unroll
        for (int j = 0; j < 4; ++j) acc[i][j] = fmaf(a[i], b2[j], acc[i][j]);
    }
    __syncthreads();
  }
  float* outB = out + ((size_t)(kh * BSZ + b) * DD) * L;
  #pragma unroll
  for (int i = 0; i < 4; ++i) {
    int o = o0 + ty * 4 + i;
    float bb = bt[kh * DD + o];
    #pragma unroll
    for (int j = 0; j < 4; ++j) {
      int l = l0 + tx * 4 + j;
      outB[(size_t)o * L + l] = fmaxf(acc[i][j] + bb, 0.f);
    }
  }
}

// ---------------------------------------------------------------------------
extern "C" void kernel_launch(void* const* d_in, const int* in_sizes, int n_in,
                              void* d_out, int out_size, void* d_ws, size_t ws_size,
                              hipStream_t stream) {
  // Inputs per setup_inputs() order
  const int*   x_pep          = (const int*)d_in[0];
  const int*   x_ss_pep       = (const int*)d_in[1];
  const int*   x_2_pep        = (const int*)d_in[2];
  const float* x_dense_pep    = (const float*)d_in[3];
  const float* x_pretrain_pep = (const float*)d_in[4];
  const int*   x_pro          = (const int*)d_in[5];
  const int*   x_ss_pro       = (const int*)d_in[6];
  const int*   x_2_pro        = (const int*)d_in[7];
  const float* x_dense_pro    = (const float*)d_in[8];
  const float* x_pretrain_pro = (const float*)d_in[9];
  const float* x_edge_pep     = (const float*)d_in[10];
  const float* x_edge_pro     = (const float*)d_in[11];
  const float* mask_pep       = (const float*)d_in[12];
  const float* mask_pro       = (const float*)d_in[13];
  const float* E_seq          = (const float*)d_in[14];
  const float* E_ss           = (const float*)d_in[15];
  const float* E_two          = (const float*)d_in[16];
  const float* W_dpep         = (const float*)d_in[17];
  const float* b_dpep         = (const float*)d_in[18];
  const float* W_dpro         = (const float*)d_in[19];
  const float* b_dpro         = (const float*)d_in[20];
  const float* W_ppep         = (const float*)d_in[21];
  const float* b_ppep         = (const float*)d_in[22];
  const float* W_ppro         = (const float*)d_in[23];
  const float* b_ppro         = (const float*)d_in[24];
  const float* Wg_pep1        = (const float*)d_in[25];
  const float* bg_pep1        = (const float*)d_in[26];
  const float* Wg_pep2        = (const float*)d_in[27];
  const float* bg_pep2        = (const float*)d_in[28];
  const float* Wg_pro1        = (const float*)d_in[29];
  const float* bg_pro1        = (const float*)d_in[30];
  const float* Wg_pro2        = (const float*)d_in[31];
  const float* bg_pro2        = (const float*)d_in[32];
  const float* Wt_pep         = (const float*)d_in[33];
  const float* bt_pep         = (const float*)d_in[34];
  const float* Wt_pro         = (const float*)d_in[35];
  const float* bt_pro         = (const float*)d_in[36];

  float* out = (float*)d_out;

  // Workspace layout (floats): enc | bufA | bufY | dinv_pep | dinv_pro
  const size_t NBUF = (size_t)BSZ * LR * DG;  // 10,485,760 floats (pro-sized)
  float* enc   = (float*)d_ws;
  float* bufA  = enc + NBUF;
  float* bufY  = bufA + NBUF;
  float* dinvP = bufY + NBUF;                 // 2048
  float* dinvR = dinvP + (size_t)BSZ * LP;    // 16384

  const int BLp = BSZ * LP;   // 2048
  const int BLr = BSZ * LR;   // 16384
  const size_t out_pro_off = (size_t)KH * BSZ * DD * LP;  // 1,835,008

  // ---------------- PEP branch ----------------
  encoder_light<<<BLp, 128, 0, stream>>>(x_pep, x_ss_pep, x_2_pep, x_dense_pep, 3,
                                         E_seq, E_ss, E_two, W_dpep, b_dpep,
                                         mask_pep, enc);
  gemm_nn<<<dim3(2, BLp / 64), 256, 0, stream>>>(
      x_pretrain_pep, 1024, W_ppep, DD, enc + 512, DG,
      BLp, DD, 1024, b_ppep, nullptr, mask_pep, 0);
  degree_k<<<dim3(LP / 128, BSZ), 128, 0, stream>>>(x_edge_pep, dinvP, LP);
  gemm_nn<<<dim3(DG / 64, BLp / 64), 256, 0, stream>>>(
      enc, DG, Wg_pep1, DG, bufA, DG, BLp, DG, DG, nullptr, dinvP, nullptr, 0);
  gemm_agg<<<dim3(DG / 64, LP / 64, BSZ), 256, 0, stream>>>(
      x_edge_pep, bufA, dinvP, bg_pep1, nullptr, nullptr, bufY, LP);
  gemm_nn<<<dim3(DG / 64, BLp / 64), 256, 0, stream>>>(
      bufY, DG, Wg_pep2, DG, bufA, DG, BLp, DG, DG, nullptr, dinvP, nullptr, 0);
  gemm_agg<<<dim3(DG / 64, LP / 64, BSZ), 256, 0, stream>>>(
      x_edge_pep, bufA, dinvP, bg_pep2, enc, mask_pep, bufY, LP);
  gemm_fct<<<dim3(LP / 64, DD / 64, KH * BSZ), 256, 0, stream>>>(
      Wt_pep, bt_pep, bufY, out, LP);

  // ---------------- PRO branch ----------------
  encoder_light<<<BLr, 128, 0, stream>>>(x_pro, x_ss_pro, x_2_pro, x_dense_pro, 23,
                                         E_seq, E_ss, E_two, W_dpro, b_dpro,
                                         mask_pro, enc);
  gemm_nn<<<dim3(2, BLr / 64), 256, 0, stream>>>(
      x_pretrain_pro, 1024, W_ppro, DD, enc + 512, DG,
      BLr, DD, 1024, b_ppro, nullptr, mask_pro, 0);
  degree_k<<<dim3(LR / 128, BSZ), 128, 0, stream>>>(x_edge_pro, dinvR, LR);
  gemm_nn<<<dim3(DG / 64, BLr / 64), 256, 0, stream>>>(
      enc, DG, Wg_pro1, DG, bufA, DG, BLr, DG, DG, nullptr, dinvR, nullptr, 0);
  gemm_agg<<<dim3(DG / 64, LR / 64, BSZ), 256, 0, stream>>>(
      x_edge_pro, bufA, dinvR, bg_pro1, nullptr, nullptr, bufY, LR);
  gemm_nn<<<dim3(DG / 64, BLr / 64), 256, 0, stream>>>(
      bufY, DG, Wg_pro2, DG, bufA, DG, BLr, DG, DG, nullptr, dinvR, nullptr, 0);
  gemm_agg<<<dim3(DG / 64, LR / 64, BSZ), 256, 0, stream>>>(
      x_edge_pro, bufA, dinvR, bg_pro2, enc, mask_pro, bufY, LR);
  gemm_fct<<<dim3(LR / 64, DD / 64, KH * BSZ), 256, 0, stream>>>(
      Wt_pro, bt_pro, bufY, out + out_pro_off, LR);
}

// Round 2
// 1784.904 us; speedup vs baseline: 1.2750x; 1.2750x over previous
//
#include <hip/hip_runtime.h>
#include <hip/hip_bf16.h>

// Problem constants
#define BSZ 16
#define LP 128
#define LR 1024
#define DD 128
#define DG 640
#define KH 7

// ---------------------------------------------------------------------------
// Light encoder kernel: embeddings (3 x 128 cols) + small dense matmul (128)
// ---------------------------------------------------------------------------
__global__ __launch_bounds__(128) void encoder_light(
    const int* __restrict__ xs, const int* __restrict__ xss,
    const int* __restrict__ x2, const float* __restrict__ xd, int Kd,
    const float* __restrict__ Eseq, const float* __restrict__ Ess,
    const float* __restrict__ Etwo,
    const float* __restrict__ Wd, const float* __restrict__ bd,
    const float* __restrict__ mask, float* __restrict__ enc) {
  int row = blockIdx.x;
  int t = threadIdx.x;
  float m = mask[row];
  int i0 = xs[row], i1 = xss[row], i2 = x2[row];
  float* e = enc + (size_t)row * DG;
  e[t]       = Eseq[i0 * DD + t] * m;
  e[DD + t]  = Ess[i1 * DD + t] * m;
  e[2*DD + t]= Etwo[i2 * DD + t] * m;
  float acc = bd[t];
  const float* xr = xd + (size_t)row * Kd;
  for (int i = 0; i < Kd; ++i) acc = fmaf(xr[i], Wd[i * DD + t], acc);
  e[3*DD + t] = acc * m;
}

// ---------------------------------------------------------------------------
// Degree pipeline: zero -> partial counts (parallel over row chunks) -> rsqrt
// deg[b,c] = sum_r (adj[b,r,c]!=0 || r==c)
// ---------------------------------------------------------------------------
__global__ __launch_bounds__(256) void zero_f32(float* __restrict__ p, int n) {
  int i = blockIdx.x * 256 + threadIdx.x;
  if (i < n) p[i] = 0.f;
}

__global__ void degree_partial(const float* __restrict__ adj,
                               float* __restrict__ deg, int L, int rpc) {
  int b = blockIdx.y;
  int rc = blockIdx.z;
  int c4 = (blockIdx.x * blockDim.x + threadIdx.x) * 4;
  if (c4 >= L) return;
  const float* adjB = adj + (size_t)b * L * L;
  int r0 = rc * rpc;
  float cx = 0.f, cy = 0.f, cz = 0.f, cw = 0.f;
  for (int r = r0; r < r0 + rpc; ++r) {
    float4 a = *(const float4*)(adjB + (size_t)r * L + c4);
    cx += (a.x != 0.f || r == c4)     ? 1.f : 0.f;
    cy += (a.y != 0.f || r == c4 + 1) ? 1.f : 0.f;
    cz += (a.z != 0.f || r == c4 + 2) ? 1.f : 0.f;
    cw += (a.w != 0.f || r == c4 + 3) ? 1.f : 0.f;
  }
  float* d = deg + b * L + c4;
  atomicAdd(d + 0, cx);
  atomicAdd(d + 1, cy);
  atomicAdd(d + 2, cz);
  atomicAdd(d + 3, cw);
}

__global__ __launch_bounds__(256) void rsqrt_k(const float* __restrict__ deg,
                                               float* __restrict__ dinv, int n) {
  int i = blockIdx.x * 256 + threadIdx.x;
  if (i < n) dinv[i] = rsqrtf(deg[i]);
}

// ---------------------------------------------------------------------------
// Generic tiled GEMM (NN): C[m,n] = sum_k A[m,k]*B[k,n]
// epilogue: v = acc*rowscale[m] + bias[n]; (relu); v *= rowmask[m]
// ---------------------------------------------------------------------------
__global__ __launch_bounds__(256) void gemm_nn(
    const float* __restrict__ A, int lda, const float* __restrict__ B, int ldb,
    float* __restrict__ C, int ldc, int M, int N, int K,
    const float* __restrict__ bias, const float* __restrict__ rowscale,
    const float* __restrict__ rowmask, int relu) {
  __shared__ float As[16][68];
  __shared__ float Bs[16][68];
  int tid = threadIdx.x;
  int tx = tid & 15, ty = tid >> 4;
  int m0 = blockIdx.y * 64, n0 = blockIdx.x * 64;
  float acc[4][4] = {};
  for (int k0 = 0; k0 < K; k0 += 16) {
    #pragma unroll
    for (int s = 0; s < 4; ++s) {
      int idx = tid + s * 256;
      int kk = idx & 15, mm = idx >> 4;
      As[kk][mm] = A[(size_t)(m0 + mm) * lda + k0 + kk];
    }
    #pragma unroll
    for (int s = 0; s < 4; ++s) {
      int idx = tid + s * 256;
      int nn = idx & 63, kk = idx >> 6;
      Bs[kk][nn] = B[(size_t)(k0 + kk) * ldb + n0 + nn];
    }
    __syncthreads();
    #pragma unroll
    for (int kk = 0; kk < 16; ++kk) {
      float a[4], b[4];
      #pragma unroll
      for (int i = 0; i < 4; ++i) a[i] = As[kk][ty * 4 + i];
      #pragma unroll
      for (int j = 0; j < 4; ++j) b[j] = Bs[kk][tx * 4 + j];
      #pragma unroll
      for (int i = 0; i < 4; ++i)
        #pragma unroll
        for (int j = 0; j < 4; ++j) acc[i][j] = fmaf(a[i], b[j], acc[i][j]);
    }
    __syncthreads();
  }
  #pragma unroll
  for (int i = 0; i < 4; ++i) {
    int m = m0 + ty * 4 + i;
    float rs = rowscale ? rowscale[m] : 1.f;
    float rm = rowmask ? rowmask[m] : 1.f;
    #pragma unroll
    for (int j = 0; j < 4; ++j) {
      int n = n0 + tx * 4 + j;
      float v = acc[i][j] * rs;
      if (bias) v += bias[n];
      if (relu) v = fmaxf(v, 0.f);
      v *= rm;
      C[(size_t)m * ldc + n] = v;
    }
  }
}

// ---------------------------------------------------------------------------
// Aggregation GEMM (TN, batched over z=b):
// Y[b,c,d] = relu( dinv[b,c] * sum_r Ahat[b,r,c]*X[b,r,d] + bias[d] (+E) ) * mask
// ---------------------------------------------------------------------------
__global__ __launch_bounds__(256) void gemm_agg(
    const float* __restrict__ adj, const float* __restrict__ X,
    const float* __restrict__ dinv, const float* __restrict__ bias,
    const float* __restrict__ addE, const float* __restrict__ rowmask,
    float* __restrict__ Y, int L) {
  int b = blockIdx.z;
  __shared__ float As[16][68];  // [r][c]
  __shared__ float Bs[16][68];  // [r][d]
  int tid = threadIdx.x;
  int tx = tid & 15, ty = tid >> 4;
  int c0 = blockIdx.y * 64, d0 = blockIdx.x * 64;
  const float* adjB = adj + (size_t)b * L * L;
  const float* XB = X + (size_t)b * L * DG;
  float acc[4][4] = {};
  for (int r0 = 0; r0 < L; r0 += 16) {
    #pragma unroll
    for (int s = 0; s < 4; ++s) {
      int idx = tid + s * 256;
      int mm = idx & 63, kk = idx >> 6;
      int r = r0 + kk, c = c0 + mm;
      float a = adjB[(size_t)r * L + c];
      As[kk][mm] = (a != 0.f || r == c) ? 1.f : 0.f;
    }
    #pragma unroll
    for (int s = 0; s < 4; ++s) {
      int idx = tid + s * 256;
      int nn = idx & 63, kk = idx >> 6;
      Bs[kk][nn] = XB[(size_t)(r0 + kk) * DG + d0 + nn];
    }
    __syncthreads();
    #pragma unroll
    for (int kk = 0; kk < 16; ++kk) {
      float a[4], b2[4];
      #pragma unroll
      for (int i = 0; i < 4; ++i) a[i] = As[kk][ty * 4 + i];
      #pragma unroll
      for (int j = 0; j < 4; ++j) b2[j] = Bs[kk][tx * 4 + j];
      #pragma unroll
      for (int i = 0; i < 4; ++i)
        #pragma unroll
        for (int j = 0; j < 4; ++j) acc[i][j] = fmaf(a[i], b2[j], acc[i][j]);
    }
    __syncthreads();
  }
  #pragma unroll
  for (int i = 0; i < 4; ++i) {
    int c = c0 + ty * 4 + i;
    float di = dinv[b * L + c];
    float rm = rowmask ? rowmask[b * L + c] : 1.f;
    #pragma unroll
    for (int j = 0; j < 4; ++j) {
      int d = d0 + tx * 4 + j;
      float v = acc[i][j] * di + bias[d];
      if (addE) v += addE[((size_t)(b * L + c)) * DG + d];
      v = fmaxf(v, 0.f);
      v *= rm;
      Y[((size_t)(b * L + c)) * DG + d] = v;
    }
  }
}

// ---------------------------------------------------------------------------
// FC-trans GEMM (batched over z = kh*B + b).
// ---------------------------------------------------------------------------
__global__ __launch_bounds__(256) void gemm_fct(
    const float* __restrict__ Wt, const float* __restrict__ bt,
    const float* __restrict__ f, float* __restrict__ out, int L) {
  int z = blockIdx.z;
  int kh = z / BSZ, b = z % BSZ;
  __shared__ float As[16][68];  // [d][o]
  __shared__ float Bs[16][68];  // [d][l]
  int tid = threadIdx.x;
  int tx = tid & 15, ty = tid >> 4;
  int o0 = blockIdx.y * 64, l0 = blockIdx.x * 64;
  const float* Wk = Wt + (size_t)kh * DD * DG;
  const float* fB = f + (size_t)b * L * DG;
  float acc[4][4] = {};
  for (int k0 = 0; k0 < DG; k0 += 16) {
    #pragma unroll
    for (int s = 0; s < 4; ++s) {
      int idx = tid + s * 256;
      int kk = idx & 15, mm = idx >> 4;
      As[kk][mm] = Wk[(size_t)(o0 + mm) * DG + k0 + kk];
    }
    #pragma unroll
    for (int s = 0; s < 4; ++s) {
      int idx = tid + s * 256;
      int kk = idx & 15, nn = idx >> 4;
      Bs[kk][nn] = fB[(size_t)(l0 + nn) * DG + k0 + kk];
    }
    __syncthreads();
    #pragma unroll
    for (int kk = 0; kk < 16; ++kk) {
      float a[4], b2[4];
      #pragma unroll
      for (int i = 0; i < 4; ++i) a[i] = As[kk][ty * 4 + i];
      #pragma unroll
      for (int j = 0; j < 4; ++j) b2[j] = Bs[kk][tx * 4 + j];
      #pragma unroll
      for (int i = 0; i < 4; ++i)
        #pragma unroll
        for (int j = 0; j < 4; ++j) acc[i][j] = fmaf(a[i], b2[j], acc[i][j]);
    }
    __syncthreads();
  }
  float* outB = out + ((size_t)(kh * BSZ + b) * DD) * L;
  #pragma unroll
  for (int i = 0; i < 4; ++i) {
    int o = o0 + ty * 4 + i;
    float bb = bt[kh * DD + o];
    #pragma unroll
    for (int j = 0; j < 4; ++j) {
      int l = l0 + tx * 4 + j;
      outB[(size_t)o * L + l] = fmaxf(acc[i][j] + bb, 0.f);
    }
  }
}

// ---------------------------------------------------------------------------
extern "C" void kernel_launch(void* const* d_in, const int* in_sizes, int n_in,
                              void* d_out, int out_size, void* d_ws, size_t ws_size,
                              hipStream_t stream) {
  const int*   x_pep          = (const int*)d_in[0];
  const int*   x_ss_pep       = (const int*)d_in[1];
  const int*   x_2_pep        = (const int*)d_in[2];
  const float* x_dense_pep    = (const float*)d_in[3];
  const float* x_pretrain_pep = (const float*)d_in[4];
  const int*   x_pro          = (const int*)d_in[5];
  const int*   x_ss_pro       = (const int*)d_in[6];
  const int*   x_2_pro        = (const int*)d_in[7];
  const float* x_dense_pro    = (const float*)d_in[8];
  const float* x_pretrain_pro = (const float*)d_in[9];
  const float* x_edge_pep     = (const float*)d_in[10];
  const float* x_edge_pro     = (const float*)d_in[11];
  const float* mask_pep       = (const float*)d_in[12];
  const float* mask_pro       = (const float*)d_in[13];
  const float* E_seq          = (const float*)d_in[14];
  const float* E_ss           = (const float*)d_in[15];
  const float* E_two          = (const float*)d_in[16];
  const float* W_dpep         = (const float*)d_in[17];
  const float* b_dpep         = (const float*)d_in[18];
  const float* W_dpro         = (const float*)d_in[19];
  const float* b_dpro         = (const float*)d_in[20];
  const float* W_ppep         = (const float*)d_in[21];
  const float* b_ppep         = (const float*)d_in[22];
  const float* W_ppro         = (const float*)d_in[23];
  const float* b_ppro         = (const float*)d_in[24];
  const float* Wg_pep1        = (const float*)d_in[25];
  const float* bg_pep1        = (const float*)d_in[26];
  const float* Wg_pep2        = (const float*)d_in[27];
  const float* bg_pep2        = (const float*)d_in[28];
  const float* Wg_pro1        = (const float*)d_in[29];
  const float* bg_pro1        = (const float*)d_in[30];
  const float* Wg_pro2        = (const float*)d_in[31];
  const float* bg_pro2        = (const float*)d_in[32];
  const float* Wt_pep         = (const float*)d_in[33];
  const float* bt_pep         = (const float*)d_in[34];
  const float* Wt_pro         = (const float*)d_in[35];
  const float* bt_pro         = (const float*)d_in[36];

  float* out = (float*)d_out;

  // Workspace layout (floats): enc | bufA | bufY | dinvP | dinvR | degP | degR
  const size_t NBUF = (size_t)BSZ * LR * DG;
  float* enc   = (float*)d_ws;
  float* bufA  = enc + NBUF;
  float* bufY  = bufA + NBUF;
  float* dinvP = bufY + NBUF;
  float* dinvR = dinvP + (size_t)BSZ * LP;
  float* degP  = dinvR + (size_t)BSZ * LR;
  float* degR  = degP + (size_t)BSZ * LP;

  const int BLp = BSZ * LP;   // 2048
  const int BLr = BSZ * LR;   // 16384
  const size_t out_pro_off = (size_t)KH * BSZ * DD * LP;

  // ---------------- PEP branch ----------------
  encoder_light<<<BLp, 128, 0, stream>>>(x_pep, x_ss_pep, x_2_pep, x_dense_pep, 3,
                                         E_seq, E_ss, E_two, W_dpep, b_dpep,
                                         mask_pep, enc);
  gemm_nn<<<dim3(2, BLp / 64), 256, 0, stream>>>(
      x_pretrain_pep, 1024, W_ppep, DD, enc + 512, DG,
      BLp, DD, 1024, b_ppep, nullptr, mask_pep, 0);
  zero_f32<<<(BLp + 255) / 256, 256, 0, stream>>>(degP, BLp);
  degree_partial<<<dim3(1, BSZ, 4), 64, 0, stream>>>(x_edge_pep, degP, LP, 32);
  rsqrt_k<<<(BLp + 255) / 256, 256, 0, stream>>>(degP, dinvP, BLp);
  gemm_nn<<<dim3(DG / 64, BLp / 64), 256, 0, stream>>>(
      enc, DG, Wg_pep1, DG, bufA, DG, BLp, DG, DG, nullptr, dinvP, nullptr, 0);
  gemm_agg<<<dim3(DG / 64, LP / 64, BSZ), 256, 0, stream>>>(
      x_edge_pep, bufA, dinvP, bg_pep1, nullptr, nullptr, bufY, LP);
  gemm_nn<<<dim3(DG / 64, BLp / 64), 256, 0, stream>>>(
      bufY, DG, Wg_pep2, DG, bufA, DG, BLp, DG, DG, nullptr, dinvP, nullptr, 0);
  gemm_agg<<<dim3(DG / 64, LP / 64, BSZ), 256, 0, stream>>>(
      x_edge_pep, bufA, dinvP, bg_pep2, enc, mask_pep, bufY, LP);
  gemm_fct<<<dim3(LP / 64, DD / 64, KH * BSZ), 256, 0, stream>>>(
      Wt_pep, bt_pep, bufY, out, LP);

  // ---------------- PRO branch ----------------
  encoder_light<<<BLr, 128, 0, stream>>>(x_pro, x_ss_pro, x_2_pro, x_dense_pro, 23,
                                         E_seq, E_ss, E_two, W_dpro, b_dpro,
                                         mask_pro, enc);
  gemm_nn<<<dim3(2, BLr / 64), 256, 0, stream>>>(
      x_pretrain_pro, 1024, W_ppro, DD, enc + 512, DG,
      BLr, DD, 1024, b_ppro, nullptr, mask_pro, 0);
  zero_f32<<<(BLr + 255) / 256, 256, 0, stream>>>(degR, BLr);
  degree_partial<<<dim3(1, BSZ, 16), 256, 0, stream>>>(x_edge_pro, degR, LR, 64);
  rsqrt_k<<<(BLr + 255) / 256, 256, 0, stream>>>(degR, dinvR, BLr);
  gemm_nn<<<dim3(DG / 64, BLr / 64), 256, 0, stream>>>(
      enc, DG, Wg_pro1, DG, bufA, DG, BLr, DG, DG, nullptr, dinvR, nullptr, 0);
  gemm_agg<<<dim3(DG / 64, LR / 64, BSZ), 256, 0, stream>>>(
      x_edge_pro, bufA, dinvR, bg_pro1, nullptr, nullptr, bufY, LR);
  gemm_nn<<<dim3(DG / 64, BLr / 64), 256, 0, stream>>>(
      bufY, DG, Wg_pro2, DG, bufA, DG, BLr, DG, DG, nullptr, dinvR, nullptr, 0);
  gemm_agg<<<dim3(DG / 64, LR / 64, BSZ), 256, 0, stream>>>(
      x_edge_pro, bufA, dinvR, bg_pro2, enc, mask_pro, bufY, LR);
  gemm_fct<<<dim3(LR / 64, DD / 64, KH * BSZ), 256, 0, stream>>>(
      Wt_pro, bt_pro, bufY, out + out_pro_off, LR);
}

// Round 3
// 827.139 us; speedup vs baseline: 2.7513x; 2.1579x over previous
//
#include <hip/hip_runtime.h>
#include <hip/hip_bf16.h>

// Problem constants
#define BSZ 16
#define LP 128
#define LR 1024
#define DD 128
#define DG 640
#define KH 7

typedef __bf16 bf16x8 __attribute__((ext_vector_type(8)));
typedef __bf16 bf16x4v __attribute__((ext_vector_type(4)));
typedef float f32x4 __attribute__((ext_vector_type(4)));

// ---------------------------------------------------------------------------
// Encoder: embeddings (3 x 128 cols) + small dense matmul -> bf16 enc [BL,640]
// ---------------------------------------------------------------------------
__global__ __launch_bounds__(128) void encoder_bf16(
    const int* __restrict__ xs, const int* __restrict__ xss,
    const int* __restrict__ x2, const float* __restrict__ xd, int Kd,
    const float* __restrict__ Eseq, const float* __restrict__ Ess,
    const float* __restrict__ Etwo,
    const float* __restrict__ Wd, const float* __restrict__ bd,
    const float* __restrict__ mask, __bf16* __restrict__ enc) {
  int row = blockIdx.x;
  int t = threadIdx.x;
  float m = mask[row];
  int i0 = xs[row], i1 = xss[row], i2 = x2[row];
  __bf16* e = enc + (size_t)row * DG;
  e[t]        = (__bf16)(Eseq[i0 * DD + t] * m);
  e[DD + t]   = (__bf16)(Ess[i1 * DD + t] * m);
  e[2*DD + t] = (__bf16)(Etwo[i2 * DD + t] * m);
  float acc = bd[t];
  const float* xr = xd + (size_t)row * Kd;
  for (int i = 0; i < Kd; ++i) acc = fmaf(xr[i], Wd[i * DD + t], acc);
  e[3*DD + t] = (__bf16)(acc * m);
}

// ---------------------------------------------------------------------------
// Small utility kernels
// ---------------------------------------------------------------------------
__global__ __launch_bounds__(256) void zero_f32(float* __restrict__ p, int n) {
  int i = blockIdx.x * 256 + threadIdx.x;
  if (i < n) p[i] = 0.f;
}

__global__ __launch_bounds__(256) void rsqrt_k(const float* __restrict__ deg,
                                               float* __restrict__ dinv, int n) {
  int i = blockIdx.x * 256 + threadIdx.x;
  if (i < n) dinv[i] = rsqrtf(deg[i]);
}

// flat f32 -> bf16 (n4 = n/4)
__global__ __launch_bounds__(256) void cvt_bf16(const float* __restrict__ in,
                                                __bf16* __restrict__ out, int n4) {
  int i = blockIdx.x * 256 + threadIdx.x;
  if (i < n4) {
    float4 v = ((const float4*)in)[i];
    bf16x4v o;
    o.x = (__bf16)v.x; o.y = (__bf16)v.y; o.z = (__bf16)v.z; o.w = (__bf16)v.w;
    ((bf16x4v*)out)[i] = o;
  }
}

// f32 [R,C] -> bf16 [C,R]   (R,C multiples of 32)
__global__ __launch_bounds__(256) void cvt_T_bf16(const float* __restrict__ in,
                                                  __bf16* __restrict__ out,
                                                  int R, int C) {
  __shared__ float T[32][33];
  int r0 = blockIdx.y * 32, c0 = blockIdx.x * 32;
  int t = threadIdx.x;
  #pragma unroll
  for (int s = 0; s < 4; ++s) {
    int idx = t + s * 256;
    int r = idx >> 5, c = idx & 31;
    T[r][c] = in[(size_t)(r0 + r) * C + c0 + c];
  }
  __syncthreads();
  #pragma unroll
  for (int s = 0; s < 4; ++s) {
    int idx = t + s * 256;
    int c = idx >> 5, r = idx & 31;
    out[(size_t)(c0 + c) * R + r0 + r] = (__bf16)T[r][c];
  }
}

// bf16 [R,C] -> bf16 [C,R]   (R,C multiples of 32)
__global__ __launch_bounds__(256) void tr_bf16(const __bf16* __restrict__ in,
                                               __bf16* __restrict__ out,
                                               int R, int C) {
  __shared__ ushort T[32][34];
  int r0 = blockIdx.y * 32, c0 = blockIdx.x * 32;
  int t = threadIdx.x;
  const ushort* inu = (const ushort*)in;
  ushort* outu = (ushort*)out;
  #pragma unroll
  for (int s = 0; s < 4; ++s) {
    int idx = t + s * 256;
    int r = idx >> 5, c = idx & 31;
    T[r][c] = inu[(size_t)(r0 + r) * C + c0 + c];
  }
  __syncthreads();
  #pragma unroll
  for (int s = 0; s < 4; ++s) {
    int idx = t + s * 256;
    int c = idx >> 5, r = idx & 31;
    outu[(size_t)(c0 + c) * R + r0 + r] = T[r][c];
  }
}

// adj f32 [b,r,c] -> AhatT bf16 [b,c,r] (binarized + self loops) + column deg
// grid: (L/64, L/64, B); deg must be pre-zeroed.
__global__ __launch_bounds__(256) void prep_adj(
    const float* __restrict__ adj, __bf16* __restrict__ AhatT,
    float* __restrict__ deg, int L) {
  __shared__ float T[64][65];
  int b = blockIdx.z;
  int c0 = blockIdx.x * 64, r0 = blockIdx.y * 64;
  int t = threadIdx.x;
  const float* adjB = adj + (size_t)b * L * L;
  #pragma unroll
  for (int s = 0; s < 16; ++s) {
    int idx = t + s * 256;
    int r = idx >> 6, c = idx & 63;
    float a = adjB[(size_t)(r0 + r) * L + c0 + c];
    T[r][c] = (a != 0.f || (r0 + r) == (c0 + c)) ? 1.f : 0.f;
  }
  __syncthreads();
  if (t < 64) {
    float s = 0.f;
    #pragma unroll 8
    for (int r = 0; r < 64; ++r) s += T[r][t];
    atomicAdd(deg + b * L + c0 + t, s);
  }
  __bf16* outB = AhatT + (size_t)b * L * L;
  #pragma unroll
  for (int s = 0; s < 16; ++s) {
    int idx = t + s * 256;
    int c = idx >> 6, r = idx & 63;
    outB[(size_t)(c0 + c) * L + r0 + r] = (__bf16)T[r][c];
  }
}

// ---------------------------------------------------------------------------
// Generic bf16 MFMA GEMM. C[m,n] = sum_k A[m,k] * Bt[n,k]   (fp32 accum)
// 128x128 block tile, BK=32, 4 waves each 64x64 via 16x16x32 MFMA.
// grid: (N/128, M/128, Z).  z: kh=z/zdiv selects A/bias, jb=z%zdiv selects B
// (zdiv=1 -> both stride by z). Epilogue:
//   v = acc*rowscale[z*sRz+m]; v += bias_per_m? bias[kh*biasZ+m] : bias[n];
//   v += addE[z*sEz + m*lde + n]; relu; v *= rowmask[z*sRz+m];
// Store f32 (outf32) or bf16.
// ---------------------------------------------------------------------------
__global__ __launch_bounds__(256) void mfma_gemm(
    const __bf16* __restrict__ A, long long sAz, int lda,
    const __bf16* __restrict__ Bt, long long sBz, int ldb,
    void* __restrict__ Cout, long long sCz, int ldc, int outf32,
    int K, int zdiv,
    const float* __restrict__ bias, int bias_per_m, int biasZ,
    const float* __restrict__ rowscale, const float* __restrict__ rowmask,
    long long sRz,
    const __bf16* __restrict__ addE, long long sEz, int lde, int relu) {
  __shared__ __align__(16) ushort As[128 * 40];
  __shared__ __align__(16) ushort Bs[128 * 40];
  int z = blockIdx.z;
  int kh = z / zdiv;
  int jb = (zdiv > 1) ? (z % zdiv) : z;
  const ushort* Ab = (const ushort*)(A + (size_t)kh * sAz);
  const ushort* Bb = (const ushort*)(Bt + (size_t)jb * sBz);
  int m0 = blockIdx.y * 128, n0 = blockIdx.x * 128;
  int t = threadIdx.x;
  int wave = t >> 6, lane = t & 63;
  int quad = lane >> 4, l16 = lane & 15;
  int wm = (wave >> 1) * 64, wn = (wave & 1) * 64;
  int r1 = t >> 2, o1 = (t & 3) * 8;

  f32x4 acc[4][4];
  #pragma unroll
  for (int i = 0; i < 4; ++i)
    #pragma unroll
    for (int j = 0; j < 4; ++j) acc[i][j] = (f32x4){0.f, 0.f, 0.f, 0.f};

  for (int k0 = 0; k0 < K; k0 += 32) {
    int4 a0 = *(const int4*)(Ab + (size_t)(m0 + r1) * lda + k0 + o1);
    int4 a1 = *(const int4*)(Ab + (size_t)(m0 + r1 + 64) * lda + k0 + o1);
    int4 b0 = *(const int4*)(Bb + (size_t)(n0 + r1) * ldb + k0 + o1);
    int4 b1 = *(const int4*)(Bb + (size_t)(n0 + r1 + 64) * ldb + k0 + o1);
    __syncthreads();
    *(int4*)&As[r1 * 40 + o1] = a0;
    *(int4*)&As[(r1 + 64) * 40 + o1] = a1;
    *(int4*)&Bs[r1 * 40 + o1] = b0;
    *(int4*)&Bs[(r1 + 64) * 40 + o1] = b1;
    __syncthreads();
    bf16x8 af[4], bfr[4];
    #pragma unroll
    for (int fi = 0; fi < 4; ++fi)
      af[fi] = *(const bf16x8*)&As[(wm + fi * 16 + l16) * 40 + quad * 8];
    #pragma unroll
    for (int fj = 0; fj < 4; ++fj)
      bfr[fj] = *(const bf16x8*)&Bs[(wn + fj * 16 + l16) * 40 + quad * 8];
    #pragma unroll
    for (int fi = 0; fi < 4; ++fi)
      #pragma unroll
      for (int fj = 0; fj < 4; ++fj)
        acc[fi][fj] = __builtin_amdgcn_mfma_f32_16x16x32_bf16(
            af[fi], bfr[fj], acc[fi][fj], 0, 0, 0);
  }

  const float* biasB = bias ? bias + (size_t)kh * biasZ : nullptr;
  long long rowOff = (long long)z * sRz;
  const __bf16* Eb = addE ? addE + (size_t)z * sEz : nullptr;
  float* cf = (float*)Cout + (size_t)z * sCz;
  __bf16* cb = (__bf16*)Cout + (size_t)z * sCz;
  #pragma unroll
  for (int fi = 0; fi < 4; ++fi) {
    #pragma unroll
    for (int r = 0; r < 4; ++r) {
      int m = m0 + wm + fi * 16 + quad * 4 + r;
      float rs = rowscale ? rowscale[rowOff + m] : 1.f;
      float rm = rowmask ? rowmask[rowOff + m] : 1.f;
      float bm = (biasB && bias_per_m) ? biasB[m] : 0.f;
      #pragma unroll
      for (int fj = 0; fj < 4; ++fj) {
        int n = n0 + wn + fj * 16 + l16;
        float v = acc[fi][fj][r] * rs;
        if (biasB) v += bias_per_m ? bm : biasB[n];
        if (Eb) v += (float)Eb[(size_t)m * lde + n];
        if (relu) v = fmaxf(v, 0.f);
        v *= rm;
        if (outf32) cf[(size_t)m * ldc + n] = v;
        else cb[(size_t)m * ldc + n] = (__bf16)v;
      }
    }
  }
}

// ---------------------------------------------------------------------------
extern "C" void kernel_launch(void* const* d_in, const int* in_sizes, int n_in,
                              void* d_out, int out_size, void* d_ws, size_t ws_size,
                              hipStream_t stream) {
  const int*   x_pep          = (const int*)d_in[0];
  const int*   x_ss_pep       = (const int*)d_in[1];
  const int*   x_2_pep        = (const int*)d_in[2];
  const float* x_dense_pep    = (const float*)d_in[3];
  const float* x_pretrain_pep = (const float*)d_in[4];
  const int*   x_pro          = (const int*)d_in[5];
  const int*   x_ss_pro       = (const int*)d_in[6];
  const int*   x_2_pro        = (const int*)d_in[7];
  const float* x_dense_pro    = (const float*)d_in[8];
  const float* x_pretrain_pro = (const float*)d_in[9];
  const float* x_edge_pep     = (const float*)d_in[10];
  const float* x_edge_pro     = (const float*)d_in[11];
  const float* mask_pep       = (const float*)d_in[12];
  const float* mask_pro       = (const float*)d_in[13];
  const float* E_seq          = (const float*)d_in[14];
  const float* E_ss           = (const float*)d_in[15];
  const float* E_two          = (const float*)d_in[16];
  const float* W_dpep         = (const float*)d_in[17];
  const float* b_dpep         = (const float*)d_in[18];
  const float* W_dpro         = (const float*)d_in[19];
  const float* b_dpro         = (const float*)d_in[20];
  const float* W_ppep         = (const float*)d_in[21];
  const float* b_ppep         = (const float*)d_in[22];
  const float* W_ppro         = (const float*)d_in[23];
  const float* b_ppro         = (const float*)d_in[24];
  const float* Wg_pep1        = (const float*)d_in[25];
  const float* bg_pep1        = (const float*)d_in[26];
  const float* Wg_pep2        = (const float*)d_in[27];
  const float* bg_pep2        = (const float*)d_in[28];
  const float* Wg_pro1        = (const float*)d_in[29];
  const float* bg_pro1        = (const float*)d_in[30];
  const float* Wg_pro2        = (const float*)d_in[31];
  const float* bg_pro2        = (const float*)d_in[32];
  const float* Wt_pep         = (const float*)d_in[33];
  const float* bt_pep         = (const float*)d_in[34];
  const float* Wt_pro         = (const float*)d_in[35];
  const float* bt_pro         = (const float*)d_in[36];

  float* out = (float*)d_out;

  const int BLp = BSZ * LP;   // 2048
  const int BLr = BSZ * LR;   // 16384
  const size_t out_pro_off = (size_t)KH * BSZ * DD * LP;

  // Workspace layout (bf16 elements unless noted). Total ~123.7 MB.
  char* w = (char*)d_ws;
  __bf16* buf0  = (__bf16*)w;                 w += (size_t)16777216 * 2;  // XpB / AhatT
  __bf16* encB  = (__bf16*)w;                 w += (size_t)BLr * DG * 2;
  __bf16* bufA  = (__bf16*)w;                 w += (size_t)BLr * DG * 2;
  __bf16* bufAT = (__bf16*)w;                 w += (size_t)BLr * DG * 2;
  __bf16* bufY  = (__bf16*)w;                 w += (size_t)BLr * DG * 2;
  __bf16* WppTpep = (__bf16*)w;               w += (size_t)DD * 1024 * 2;
  __bf16* WppTpro = (__bf16*)w;               w += (size_t)DD * 1024 * 2;
  __bf16* Wg1Tpep = (__bf16*)w;               w += (size_t)DG * DG * 2;
  __bf16* Wg2Tpep = (__bf16*)w;               w += (size_t)DG * DG * 2;
  __bf16* Wg1Tpro = (__bf16*)w;               w += (size_t)DG * DG * 2;
  __bf16* Wg2Tpro = (__bf16*)w;               w += (size_t)DG * DG * 2;
  __bf16* WtBpep  = (__bf16*)w;               w += (size_t)KH * DD * DG * 2;
  __bf16* WtBpro  = (__bf16*)w;               w += (size_t)KH * DD * DG * 2;
  float* degP  = (float*)w;                   w += (size_t)BLp * 4;
  float* dinvP = (float*)w;                   w += (size_t)BLp * 4;
  float* degR  = (float*)w;                   w += (size_t)BLr * 4;
  float* dinvR = (float*)w;                   w += (size_t)BLr * 4;

  // ---- weight conversions (once) ----
  cvt_T_bf16<<<dim3(DD / 32, 1024 / 32), 256, 0, stream>>>(W_ppep, WppTpep, 1024, DD);
  cvt_T_bf16<<<dim3(DD / 32, 1024 / 32), 256, 0, stream>>>(W_ppro, WppTpro, 1024, DD);
  cvt_T_bf16<<<dim3(DG / 32, DG / 32), 256, 0, stream>>>(Wg_pep1, Wg1Tpep, DG, DG);
  cvt_T_bf16<<<dim3(DG / 32, DG / 32), 256, 0, stream>>>(Wg_pep2, Wg2Tpep, DG, DG);
  cvt_T_bf16<<<dim3(DG / 32, DG / 32), 256, 0, stream>>>(Wg_pro1, Wg1Tpro, DG, DG);
  cvt_T_bf16<<<dim3(DG / 32, DG / 32), 256, 0, stream>>>(Wg_pro2, Wg2Tpro, DG, DG);
  cvt_bf16<<<(KH * DD * DG / 4 + 255) / 256, 256, 0, stream>>>(Wt_pep, WtBpep, KH * DD * DG / 4);
  cvt_bf16<<<(KH * DD * DG / 4 + 255) / 256, 256, 0, stream>>>(Wt_pro, WtBpro, KH * DD * DG / 4);

  // ================= PEP branch (L=128) =================
  {
    const int L = LP, BL = BLp;
    encoder_bf16<<<BL, 128, 0, stream>>>(x_pep, x_ss_pep, x_2_pep, x_dense_pep, 3,
                                         E_seq, E_ss, E_two, W_dpep, b_dpep,
                                         mask_pep, encB);
    cvt_bf16<<<(BL * 1024 / 4 + 255) / 256, 256, 0, stream>>>(
        x_pretrain_pep, buf0, BL * 1024 / 4);
    mfma_gemm<<<dim3(1, BL / 128, 1), 256, 0, stream>>>(
        buf0, 0, 1024, WppTpep, 0, 1024, encB + 512, 0, DG, 0,
        1024, 1, b_ppep, 0, 0, nullptr, mask_pep, 0, nullptr, 0, 0, 0);
    zero_f32<<<(BL + 255) / 256, 256, 0, stream>>>(degP, BL);
    prep_adj<<<dim3(L / 64, L / 64, BSZ), 256, 0, stream>>>(x_edge_pep, buf0, degP, L);
    rsqrt_k<<<(BL + 255) / 256, 256, 0, stream>>>(degP, dinvP, BL);
    // lin1
    mfma_gemm<<<dim3(DG / 128, BL / 128, 1), 256, 0, stream>>>(
        encB, 0, DG, Wg1Tpep, 0, DG, bufA, 0, DG, 0,
        DG, 1, nullptr, 0, 0, dinvP, nullptr, 0, nullptr, 0, 0, 0);
    tr_bf16<<<dim3(DG / 32, BL / 32), 256, 0, stream>>>(bufA, bufAT, BL, DG);
    // agg1
    mfma_gemm<<<dim3(DG / 128, L / 128, BSZ), 256, 0, stream>>>(
        buf0, (long long)L * L, L, bufAT, L, BL, bufY, (long long)L * DG, DG, 0,
        L, 1, bg_pep1, 0, 0, dinvP, nullptr, L, nullptr, 0, 0, 1);
    // lin2
    mfma_gemm<<<dim3(DG / 128, BL / 128, 1), 256, 0, stream>>>(
        bufY, 0, DG, Wg2Tpep, 0, DG, bufA, 0, DG, 0,
        DG, 1, nullptr, 0, 0, dinvP, nullptr, 0, nullptr, 0, 0, 0);
    tr_bf16<<<dim3(DG / 32, BL / 32), 256, 0, stream>>>(bufA, bufAT, BL, DG);
    // agg2 (+residual, +mask)
    mfma_gemm<<<dim3(DG / 128, L / 128, BSZ), 256, 0, stream>>>(
        buf0, (long long)L * L, L, bufAT, L, BL, bufY, (long long)L * DG, DG, 0,
        L, 1, bg_pep2, 0, 0, dinvP, mask_pep, L, encB, (long long)L * DG, DG, 1);
    // fct
    mfma_gemm<<<dim3(L / 128, 1, KH * BSZ), 256, 0, stream>>>(
        WtBpep, (long long)DD * DG, DG, bufY, (long long)L * DG, DG,
        out, (long long)DD * L, L, 1,
        DG, BSZ, bt_pep, 1, DD, nullptr, nullptr, 0, nullptr, 0, 0, 1);
  }

  // ================= PRO branch (L=1024) =================
  {
    const int L = LR, BL = BLr;
    encoder_bf16<<<BL, 128, 0, stream>>>(x_pro, x_ss_pro, x_2_pro, x_dense_pro, 23,
                                         E_seq, E_ss, E_two, W_dpro, b_dpro,
                                         mask_pro, encB);
    cvt_bf16<<<(BL * 1024 / 4 + 255) / 256, 256, 0, stream>>>(
        x_pretrain_pro, buf0, BL * 1024 / 4);
    mfma_gemm<<<dim3(1, BL / 128, 1), 256, 0, stream>>>(
        buf0, 0, 1024, WppTpro, 0, 1024, encB + 512, 0, DG, 0,
        1024, 1, b_ppro, 0, 0, nullptr, mask_pro, 0, nullptr, 0, 0, 0);
    zero_f32<<<(BL + 255) / 256, 256, 0, stream>>>(degR, BL);
    prep_adj<<<dim3(L / 64, L / 64, BSZ), 256, 0, stream>>>(x_edge_pro, buf0, degR, L);
    rsqrt_k<<<(BL + 255) / 256, 256, 0, stream>>>(degR, dinvR, BL);
    // lin1
    mfma_gemm<<<dim3(DG / 128, BL / 128, 1), 256, 0, stream>>>(
        encB, 0, DG, Wg1Tpro, 0, DG, bufA, 0, DG, 0,
        DG, 1, nullptr, 0, 0, dinvR, nullptr, 0, nullptr, 0, 0, 0);
    tr_bf16<<<dim3(DG / 32, BL / 32), 256, 0, stream>>>(bufA, bufAT, BL, DG);
    // agg1
    mfma_gemm<<<dim3(DG / 128, L / 128, BSZ), 256, 0, stream>>>(
        buf0, (long long)L * L, L, bufAT, L, BL, bufY, (long long)L * DG, DG, 0,
        L, 1, bg_pro1, 0, 0, dinvR, nullptr, L, nullptr, 0, 0, 1);
    // lin2
    mfma_gemm<<<dim3(DG / 128, BL / 128, 1), 256, 0, stream>>>(
        bufY, 0, DG, Wg2Tpro, 0, DG, bufA, 0, DG, 0,
        DG, 1, nullptr, 0, 0, dinvR, nullptr, 0, nullptr, 0, 0, 0);
    tr_bf16<<<dim3(DG / 32, BL / 32), 256, 0, stream>>>(bufA, bufAT, BL, DG);
    // agg2 (+residual, +mask)
    mfma_gemm<<<dim3(DG / 128, L / 128, BSZ), 256, 0, stream>>>(
        buf0, (long long)L * L, L, bufAT, L, BL, bufY, (long long)L * DG, DG, 0,
        L, 1, bg_pro2, 0, 0, dinvR, mask_pro, L, encB, (long long)L * DG, DG, 1);
    // fct
    mfma_gemm<<<dim3(L / 128, 1, KH * BSZ), 256, 0, stream>>>(
        WtBpro, (long long)DD * DG, DG, bufY, (long long)L * DG, DG,
        out + out_pro_off, (long long)DD * L, L, 1,
        DG, BSZ, bt_pro, 1, DD, nullptr, nullptr, 0, nullptr, 0, 0, 1);
  }
}

// Round 4
// 744.909 us; speedup vs baseline: 3.0551x; 1.1104x over previous
//
#include <hip/hip_runtime.h>
#include <hip/hip_bf16.h>

// Problem constants
#define BSZ 16
#define LP 128
#define LR 1024
#define DD 128
#define DG 640
#define KH 7

typedef __bf16 bf16x8 __attribute__((ext_vector_type(8)));
typedef __bf16 bf16x4v __attribute__((ext_vector_type(4)));
typedef float f32x4 __attribute__((ext_vector_type(4)));
typedef unsigned int uint32;

// ---------------------------------------------------------------------------
// Encoder: embeddings (3 x 128 cols) + small dense matmul -> bf16 enc cols 0..511
// ---------------------------------------------------------------------------
__global__ __launch_bounds__(128) void encoder_bf16(
    const int* __restrict__ xs, const int* __restrict__ xss,
    const int* __restrict__ x2, const float* __restrict__ xd, int Kd,
    const float* __restrict__ Eseq, const float* __restrict__ Ess,
    const float* __restrict__ Etwo,
    const float* __restrict__ Wd, const float* __restrict__ bd,
    const float* __restrict__ mask, __bf16* __restrict__ enc) {
  int row = blockIdx.x;
  int t = threadIdx.x;
  float m = mask[row];
  int i0 = xs[row], i1 = xss[row], i2 = x2[row];
  __bf16* e = enc + (size_t)row * DG;
  e[t]        = (__bf16)(Eseq[i0 * DD + t] * m);
  e[DD + t]   = (__bf16)(Ess[i1 * DD + t] * m);
  e[2*DD + t] = (__bf16)(Etwo[i2 * DD + t] * m);
  float acc = bd[t];
  const float* xr = xd + (size_t)row * Kd;
  for (int i = 0; i < Kd; ++i) acc = fmaf(xr[i], Wd[i * DD + t], acc);
  e[3*DD + t] = (__bf16)(acc * m);
}

// ---------------------------------------------------------------------------
// Small utility kernels
// ---------------------------------------------------------------------------
__global__ __launch_bounds__(256) void zero_f32(float* __restrict__ p, int n) {
  int i = blockIdx.x * 256 + threadIdx.x;
  if (i < n) p[i] = 0.f;
}

__global__ __launch_bounds__(256) void rsqrt_k(const float* __restrict__ deg,
                                               float* __restrict__ dinv, int n) {
  int i = blockIdx.x * 256 + threadIdx.x;
  if (i < n) dinv[i] = rsqrtf(deg[i]);
}

// flat f32 -> bf16 (n4 = n/4)
__global__ __launch_bounds__(256) void cvt_bf16(const float* __restrict__ in,
                                                __bf16* __restrict__ out, int n4) {
  int i = blockIdx.x * 256 + threadIdx.x;
  if (i < n4) {
    float4 v = ((const float4*)in)[i];
    bf16x4v o;
    o.x = (__bf16)v.x; o.y = (__bf16)v.y; o.z = (__bf16)v.z; o.w = (__bf16)v.w;
    ((bf16x4v*)out)[i] = o;
  }
}

// f32 [R,C] -> bf16 [C,R]   (R,C multiples of 32)
__global__ __launch_bounds__(256) void cvt_T_bf16(const float* __restrict__ in,
                                                  __bf16* __restrict__ out,
                                                  int R, int C) {
  __shared__ float T[32][33];
  int r0 = blockIdx.y * 32, c0 = blockIdx.x * 32;
  int t = threadIdx.x;
  #pragma unroll
  for (int s = 0; s < 4; ++s) {
    int idx = t + s * 256;
    int r = idx >> 5, c = idx & 31;
    T[r][c] = in[(size_t)(r0 + r) * C + c0 + c];
  }
  __syncthreads();
  #pragma unroll
  for (int s = 0; s < 4; ++s) {
    int idx = t + s * 256;
    int c = idx >> 5, r = idx & 31;
    out[(size_t)(c0 + c) * R + r0 + r] = (__bf16)T[r][c];
  }
}

// ---------------------------------------------------------------------------
// prep_pack: adj f32 [b,r,c] -> packed bits [b][r/32][c] (bit j = Ahat[rw*32+j][c])
// + column degree via popcount. deg must be pre-zeroed.
// grid: (ceil(L/256), L/32, B), 256 threads.
// ---------------------------------------------------------------------------
__global__ __launch_bounds__(256) void prep_pack(
    const float* __restrict__ adj, uint32* __restrict__ packed,
    float* __restrict__ deg, int L) {
  int b = blockIdx.z;
  int rw = blockIdx.y;
  int c = blockIdx.x * 256 + threadIdx.x;
  if (c >= L) return;
  const float* adjB = adj + (size_t)b * L * L;
  uint32 w = 0;
  int rbase = rw * 32;
  #pragma unroll 8
  for (int j = 0; j < 32; ++j) {
    float a = adjB[(size_t)(rbase + j) * L + c];
    if (a != 0.f || (rbase + j) == c) w |= (1u << j);
  }
  packed[((size_t)b * (L >> 5) + rw) * L + c] = w;
  atomicAdd(deg + b * L + c, (float)__popc(w));
}

// ---------------------------------------------------------------------------
// Generic bf16 MFMA GEMM (A optionally f32, converted in staging).
// C[m,n] = sum_k A[m,k] * Bt[n,k]   (fp32 accum), 128x128 tile, BK=32, 4 waves.
// grid: (N/128, M/128, Z). kh_fast=0: kh=z/zdiv, jb=z%zdiv (zdiv=1 -> both z);
// kh_fast=1: kh=z%zdiv, jb=z/zdiv. C offset = (kh*outKH + jb)*sCz.
// Epilogue: v = acc; bias per m (kh*biasZ+m) or per n; v *= colscale[n];
// relu; v *= rowmask[z*sRz+m]; store f32 or bf16.
// ---------------------------------------------------------------------------
template <int AF32>
__global__ __launch_bounds__(256) void mfma_gemm(
    const void* __restrict__ A_, long long sAz, int lda,
    const __bf16* __restrict__ Bt, long long sBz, int ldb,
    void* __restrict__ Cout, long long sCz, int ldc, int outKH, int outf32,
    int K, int zdiv, int kh_fast,
    const float* __restrict__ bias, int bias_per_m, int biasZ,
    const float* __restrict__ rowmask, long long sRz,
    const float* __restrict__ colscale, int relu) {
  __shared__ __align__(16) ushort As[128 * 40];
  __shared__ __align__(16) ushort Bs[128 * 40];
  int z = blockIdx.z;
  int kh = kh_fast ? (z % zdiv) : (z / zdiv);
  int jb = kh_fast ? (z / zdiv) : ((zdiv > 1) ? (z % zdiv) : z);
  const ushort* Bb = (const ushort*)(Bt + (size_t)jb * sBz);
  int m0 = blockIdx.y * 128, n0 = blockIdx.x * 128;
  int t = threadIdx.x;
  int wave = t >> 6, lane = t & 63;
  int quad = lane >> 4, l16 = lane & 15;
  int wm = (wave >> 1) * 64, wn = (wave & 1) * 64;
  int r1 = t >> 2, o1 = (t & 3) * 8;          // bf16 staging: 64 rows x 4 slots
  int r2 = t >> 3, o2 = (t & 7) * 4;          // f32 staging: 32 rows x 8 slots

  f32x4 acc[4][4];
  #pragma unroll
  for (int i = 0; i < 4; ++i)
    #pragma unroll
    for (int j = 0; j < 4; ++j) acc[i][j] = (f32x4){0.f, 0.f, 0.f, 0.f};

  for (int k0 = 0; k0 < K; k0 += 32) {
    int4 b0 = *(const int4*)(Bb + (size_t)(n0 + r1) * ldb + k0 + o1);
    int4 b1 = *(const int4*)(Bb + (size_t)(n0 + r1 + 64) * ldb + k0 + o1);
    if (AF32) {
      const float* Af = (const float*)A_ + (size_t)kh * sAz;
      float4 a[4];
      #pragma unroll
      for (int s = 0; s < 4; ++s) {
        int idx = t + s * 256;
        int row = idx >> 3, q = (idx & 7) * 4;
        a[s] = *(const float4*)(Af + (size_t)(m0 + row) * lda + k0 + q);
      }
      __syncthreads();
      #pragma unroll
      for (int s = 0; s < 4; ++s) {
        int idx = t + s * 256;
        int row = idx >> 3, q = (idx & 7) * 4;
        ushort4 u;
        __bf16 h;
        h = (__bf16)a[s].x; u.x = *(ushort*)&h;
        h = (__bf16)a[s].y; u.y = *(ushort*)&h;
        h = (__bf16)a[s].z; u.z = *(ushort*)&h;
        h = (__bf16)a[s].w; u.w = *(ushort*)&h;
        *(ushort4*)&As[row * 40 + q] = u;
      }
      *(int4*)&Bs[r1 * 40 + o1] = b0;
      *(int4*)&Bs[(r1 + 64) * 40 + o1] = b1;
    } else {
      const ushort* Ab = (const ushort*)((const __bf16*)A_ + (size_t)kh * sAz);
      int4 a0 = *(const int4*)(Ab + (size_t)(m0 + r1) * lda + k0 + o1);
      int4 a1 = *(const int4*)(Ab + (size_t)(m0 + r1 + 64) * lda + k0 + o1);
      __syncthreads();
      *(int4*)&As[r1 * 40 + o1] = a0;
      *(int4*)&As[(r1 + 64) * 40 + o1] = a1;
      *(int4*)&Bs[r1 * 40 + o1] = b0;
      *(int4*)&Bs[(r1 + 64) * 40 + o1] = b1;
    }
    __syncthreads();
    bf16x8 af[4], bfr[4];
    #pragma unroll
    for (int fi = 0; fi < 4; ++fi)
      af[fi] = *(const bf16x8*)&As[(wm + fi * 16 + l16) * 40 + quad * 8];
    #pragma unroll
    for (int fj = 0; fj < 4; ++fj)
      bfr[fj] = *(const bf16x8*)&Bs[(wn + fj * 16 + l16) * 40 + quad * 8];
    #pragma unroll
    for (int fi = 0; fi < 4; ++fi)
      #pragma unroll
      for (int fj = 0; fj < 4; ++fj)
        acc[fi][fj] = __builtin_amdgcn_mfma_f32_16x16x32_bf16(
            af[fi], bfr[fj], acc[fi][fj], 0, 0, 0);
    __syncthreads();
  }

  const float* biasB = bias ? bias + (size_t)kh * biasZ : nullptr;
  long long rowOff = (long long)z * sRz;
  size_t coff = (size_t)(kh * outKH + jb) * sCz;
  float* cf = (float*)Cout + coff;
  __bf16* cb = (__bf16*)Cout + coff;
  #pragma unroll
  for (int fi = 0; fi < 4; ++fi) {
    #pragma unroll
    for (int r = 0; r < 4; ++r) {
      int m = m0 + wm + fi * 16 + quad * 4 + r;
      float rm = rowmask ? rowmask[rowOff + m] : 1.f;
      float bm = (biasB && bias_per_m) ? biasB[m] : 0.f;
      #pragma unroll
      for (int fj = 0; fj < 4; ++fj) {
        int n = n0 + wn + fj * 16 + l16;
        float v = acc[fi][fj][r];
        if (biasB) v += bias_per_m ? bm : biasB[n];
        if (colscale) v *= colscale[n];
        if (relu) v = fmaxf(v, 0.f);
        v *= rm;
        if (outf32) cf[(size_t)m * ldc + n] = v;
        else cb[(size_t)m * ldc + n] = (__bf16)v;
      }
    }
  }
}

// ---------------------------------------------------------------------------
// agg_packed: Y[b,c,d] = relu(dinv[b,c]*sum_r Ahat[r,c]*Xt[d][b*L+r] + bias[d]
//                             (+encE[b,c,d])) * (mask?)
// A-fragments generated in-register from packed adjacency bits.
// Xt: [DG][B*L] bf16 (lin output, transposed, rows pre-scaled by dinv_r via
// colscale in linT). grid: (DG/128, L/128, B), 256 threads.
// ---------------------------------------------------------------------------
__global__ __launch_bounds__(256) void agg_packed(
    const uint32* __restrict__ packed, const __bf16* __restrict__ Xt, int BL,
    const float* __restrict__ dinv, const float* __restrict__ bias,
    const __bf16* __restrict__ encE, const float* __restrict__ mask,
    __bf16* __restrict__ Y, int L) {
  __shared__ __align__(16) ushort Bs[128 * 40];
  __shared__ uint32 Aw[128];
  int b = blockIdx.z;
  int m0 = blockIdx.y * 128;   // c (targets)
  int n0 = blockIdx.x * 128;   // d
  int t = threadIdx.x;
  int wave = t >> 6, lane = t & 63;
  int quad = lane >> 4, l16 = lane & 15;
  int wm = (wave >> 1) * 64, wn = (wave & 1) * 64;
  int r1 = t >> 2, o1 = (t & 3) * 8;
  const uint32* pb = packed + (size_t)b * (L >> 5) * L;
  const ushort* Bb = (const ushort*)Xt + (size_t)b * L;  // column offset b*L

  f32x4 acc[4][4];
  #pragma unroll
  for (int i = 0; i < 4; ++i)
    #pragma unroll
    for (int j = 0; j < 4; ++j) acc[i][j] = (f32x4){0.f, 0.f, 0.f, 0.f};

  for (int k0 = 0; k0 < L; k0 += 32) {
    int rw = k0 >> 5;
    int4 b0 = *(const int4*)(Bb + (size_t)(n0 + r1) * BL + k0 + o1);
    int4 b1 = *(const int4*)(Bb + (size_t)(n0 + r1 + 64) * BL + k0 + o1);
    uint32 w = 0;
    if (t < 128) w = pb[(size_t)rw * L + m0 + t];
    __syncthreads();
    *(int4*)&Bs[r1 * 40 + o1] = b0;
    *(int4*)&Bs[(r1 + 64) * 40 + o1] = b1;
    if (t < 128) Aw[t] = w;
    __syncthreads();
    bf16x8 af[4], bfr[4];
    #pragma unroll
    for (int fj = 0; fj < 4; ++fj)
      bfr[fj] = *(const bf16x8*)&Bs[(wn + fj * 16 + l16) * 40 + quad * 8];
    #pragma unroll
    for (int fi = 0; fi < 4; ++fi) {
      uint32 bits = (Aw[wm + fi * 16 + l16] >> (quad * 8)) & 0xffu;
      int4 p;
      p.x = (int)((((bits >> 0) & 1) ? 0x3F80u : 0u) | (((bits >> 1) & 1) ? 0x3F800000u : 0u));
      p.y = (int)((((bits >> 2) & 1) ? 0x3F80u : 0u) | (((bits >> 3) & 1) ? 0x3F800000u : 0u));
      p.z = (int)((((bits >> 4) & 1) ? 0x3F80u : 0u) | (((bits >> 5) & 1) ? 0x3F800000u : 0u));
      p.w = (int)((((bits >> 6) & 1) ? 0x3F80u : 0u) | (((bits >> 7) & 1) ? 0x3F800000u : 0u));
      af[fi] = *(bf16x8*)&p;
    }
    #pragma unroll
    for (int fi = 0; fi < 4; ++fi)
      #pragma unroll
      for (int fj = 0; fj < 4; ++fj)
        acc[fi][fj] = __builtin_amdgcn_mfma_f32_16x16x32_bf16(
            af[fi], bfr[fj], acc[fi][fj], 0, 0, 0);
    __syncthreads();
  }

  int gRow = b * L;
  #pragma unroll
  for (int fi = 0; fi < 4; ++fi) {
    #pragma unroll
    for (int r = 0; r < 4; ++r) {
      int m = m0 + wm + fi * 16 + quad * 4 + r;
      int gi = gRow + m;
      float di = dinv[gi];
      float rm = mask ? mask[gi] : 1.f;
      #pragma unroll
      for (int fj = 0; fj < 4; ++fj) {
        int n = n0 + wn + fj * 16 + l16;
        float v = acc[fi][fj][r] * di + bias[n];
        if (encE) v += (float)encE[(size_t)gi * DG + n];
        v = fmaxf(v, 0.f);
        v *= rm;
        Y[(size_t)gi * DG + n] = (__bf16)v;
      }
    }
  }
}

// ---------------------------------------------------------------------------
extern "C" void kernel_launch(void* const* d_in, const int* in_sizes, int n_in,
                              void* d_out, int out_size, void* d_ws, size_t ws_size,
                              hipStream_t stream) {
  const int*   x_pep          = (const int*)d_in[0];
  const int*   x_ss_pep       = (const int*)d_in[1];
  const int*   x_2_pep        = (const int*)d_in[2];
  const float* x_dense_pep    = (const float*)d_in[3];
  const float* x_pretrain_pep = (const float*)d_in[4];
  const int*   x_pro          = (const int*)d_in[5];
  const int*   x_ss_pro       = (const int*)d_in[6];
  const int*   x_2_pro        = (const int*)d_in[7];
  const float* x_dense_pro    = (const float*)d_in[8];
  const float* x_pretrain_pro = (const float*)d_in[9];
  const float* x_edge_pep     = (const float*)d_in[10];
  const float* x_edge_pro     = (const float*)d_in[11];
  const float* mask_pep       = (const float*)d_in[12];
  const float* mask_pro       = (const float*)d_in[13];
  const float* E_seq          = (const float*)d_in[14];
  const float* E_ss           = (const float*)d_in[15];
  const float* E_two          = (const float*)d_in[16];
  const float* W_dpep         = (const float*)d_in[17];
  const float* b_dpep         = (const float*)d_in[18];
  const float* W_dpro         = (const float*)d_in[19];
  const float* b_dpro         = (const float*)d_in[20];
  const float* W_ppep         = (const float*)d_in[21];
  const float* b_ppep         = (const float*)d_in[22];
  const float* W_ppro         = (const float*)d_in[23];
  const float* b_ppro         = (const float*)d_in[24];
  const float* Wg_pep1        = (const float*)d_in[25];
  const float* bg_pep1        = (const float*)d_in[26];
  const float* Wg_pep2        = (const float*)d_in[27];
  const float* bg_pep2        = (const float*)d_in[28];
  const float* Wg_pro1        = (const float*)d_in[29];
  const float* bg_pro1        = (const float*)d_in[30];
  const float* Wg_pro2        = (const float*)d_in[31];
  const float* bg_pro2        = (const float*)d_in[32];
  const float* Wt_pep         = (const float*)d_in[33];
  const float* bt_pep         = (const float*)d_in[34];
  const float* Wt_pro         = (const float*)d_in[35];
  const float* bt_pro         = (const float*)d_in[36];

  float* out = (float*)d_out;

  const int BLp = BSZ * LP;   // 2048
  const int BLr = BSZ * LR;   // 16384
  const size_t out_pro_off = (size_t)KH * BSZ * DD * LP;

  // Workspace layout
  char* w = (char*)d_ws;
  __bf16* encB   = (__bf16*)w; w += (size_t)BLr * DG * 2;
  __bf16* bufAT  = (__bf16*)w; w += (size_t)DG * BLr * 2;
  __bf16* bufY   = (__bf16*)w; w += (size_t)BLr * DG * 2;
  __bf16* WppTpep = (__bf16*)w; w += (size_t)DD * 1024 * 2;
  __bf16* WppTpro = (__bf16*)w; w += (size_t)DD * 1024 * 2;
  __bf16* Wg1Tpep = (__bf16*)w; w += (size_t)DG * DG * 2;
  __bf16* Wg2Tpep = (__bf16*)w; w += (size_t)DG * DG * 2;
  __bf16* Wg1Tpro = (__bf16*)w; w += (size_t)DG * DG * 2;
  __bf16* Wg2Tpro = (__bf16*)w; w += (size_t)DG * DG * 2;
  __bf16* WtBpep  = (__bf16*)w; w += (size_t)KH * DD * DG * 2;
  __bf16* WtBpro  = (__bf16*)w; w += (size_t)KH * DD * DG * 2;
  uint32* packedP = (uint32*)w; w += (size_t)BSZ * (LP / 32) * LP * 4;
  uint32* packedR = (uint32*)w; w += (size_t)BSZ * (LR / 32) * LR * 4;
  float* degP  = (float*)w; w += (size_t)BLp * 4;
  float* degR  = (float*)w; w += (size_t)BLr * 4;
  float* dinvP = (float*)w; w += (size_t)BLp * 4;
  float* dinvR = (float*)w; w += (size_t)BLr * 4;

  // ---- weight conversions (independent) ----
  cvt_T_bf16<<<dim3(DD / 32, 1024 / 32), 256, 0, stream>>>(W_ppep, WppTpep, 1024, DD);
  cvt_T_bf16<<<dim3(DD / 32, 1024 / 32), 256, 0, stream>>>(W_ppro, WppTpro, 1024, DD);
  cvt_T_bf16<<<dim3(DG / 32, DG / 32), 256, 0, stream>>>(Wg_pep1, Wg1Tpep, DG, DG);
  cvt_T_bf16<<<dim3(DG / 32, DG / 32), 256, 0, stream>>>(Wg_pep2, Wg2Tpep, DG, DG);
  cvt_T_bf16<<<dim3(DG / 32, DG / 32), 256, 0, stream>>>(Wg_pro1, Wg1Tpro, DG, DG);
  cvt_T_bf16<<<dim3(DG / 32, DG / 32), 256, 0, stream>>>(Wg_pro2, Wg2Tpro, DG, DG);
  cvt_bf16<<<(KH * DD * DG / 4 + 255) / 256, 256, 0, stream>>>(Wt_pep, WtBpep, KH * DD * DG / 4);
  cvt_bf16<<<(KH * DD * DG / 4 + 255) / 256, 256, 0, stream>>>(Wt_pro, WtBpro, KH * DD * DG / 4);

  // ---- adjacency prep (deg zero covers degP+degR contiguously) ----
  zero_f32<<<(BLp + BLr + 255) / 256, 256, 0, stream>>>(degP, BLp + BLr);
  prep_pack<<<dim3(1, LP / 32, BSZ), 256, 0, stream>>>(x_edge_pep, packedP, degP, LP);
  prep_pack<<<dim3(LR / 256, LR / 32, BSZ), 256, 0, stream>>>(x_edge_pro, packedR, degR, LR);
  rsqrt_k<<<(BLp + BLr + 255) / 256, 256, 0, stream>>>(degP, dinvP, BLp + BLr);

  // ================= PEP branch (L=128) =================
  {
    const int L = LP, BL = BLp;
    encoder_bf16<<<BL, 128, 0, stream>>>(x_pep, x_ss_pep, x_2_pep, x_dense_pep, 3,
                                         E_seq, E_ss, E_two, W_dpep, b_dpep,
                                         mask_pep, encB);
    // pretrain GEMM: f32 A direct, writes enc cols 512..639, mask rows
    mfma_gemm<1><<<dim3(1, BL / 128, 1), 256, 0, stream>>>(
        x_pretrain_pep, 0, 1024, WppTpep, 0, 1024, encB + 512, 0, DG, 0, 0,
        1024, 1, 0, b_ppep, 0, 0, mask_pep, 0, nullptr, 0);
    // linT1: bufAT[d][row] = dinv[row] * (enc @ W1)[row][d]
    mfma_gemm<0><<<dim3(BL / 128, DG / 128, 1), 256, 0, stream>>>(
        Wg1Tpep, 0, DG, encB, 0, DG, bufAT, 0, BL, 0, 0,
        DG, 1, 0, nullptr, 0, 0, nullptr, 0, dinvP, 0);
    agg_packed<<<dim3(DG / 128, L / 128, BSZ), 256, 0, stream>>>(
        packedP, bufAT, BL, dinvP, bg_pep1, nullptr, nullptr, bufY, L);
    // linT2
    mfma_gemm<0><<<dim3(BL / 128, DG / 128, 1), 256, 0, stream>>>(
        Wg2Tpep, 0, DG, bufY, 0, DG, bufAT, 0, BL, 0, 0,
        DG, 1, 0, nullptr, 0, 0, nullptr, 0, dinvP, 0);
    agg_packed<<<dim3(DG / 128, L / 128, BSZ), 256, 0, stream>>>(
        packedP, bufAT, BL, dinvP, bg_pep2, encB, mask_pep, bufY, L);
    // fct: z = b*KH + kh (kh_fast) so B slab stays hot across 7 heads
    mfma_gemm<0><<<dim3(L / 128, 1, KH * BSZ), 256, 0, stream>>>(
        WtBpep, (long long)DD * DG, DG, bufY, (long long)L * DG, DG,
        out, (long long)DD * L, L, BSZ, 1,
        DG, KH, 1, bt_pep, 1, DD, nullptr, 0, nullptr, 1);
  }

  // ================= PRO branch (L=1024) =================
  {
    const int L = LR, BL = BLr;
    encoder_bf16<<<BL, 128, 0, stream>>>(x_pro, x_ss_pro, x_2_pro, x_dense_pro, 23,
                                         E_seq, E_ss, E_two, W_dpro, b_dpro,
                                         mask_pro, encB);
    mfma_gemm<1><<<dim3(1, BL / 128, 1), 256, 0, stream>>>(
        x_pretrain_pro, 0, 1024, WppTpro, 0, 1024, encB + 512, 0, DG, 0, 0,
        1024, 1, 0, b_ppro, 0, 0, mask_pro, 0, nullptr, 0);
    mfma_gemm<0><<<dim3(BL / 128, DG / 128, 1), 256, 0, stream>>>(
        Wg1Tpro, 0, DG, encB, 0, DG, bufAT, 0, BL, 0, 0,
        DG, 1, 0, nullptr, 0, 0, nullptr, 0, dinvR, 0);
    agg_packed<<<dim3(DG / 128, L / 128, BSZ), 256, 0, stream>>>(
        packedR, bufAT, BL, dinvR, bg_pro1, nullptr, nullptr, bufY, L);
    mfma_gemm<0><<<dim3(BL / 128, DG / 128, 1), 256, 0, stream>>>(
        Wg2Tpro, 0, DG, bufY, 0, DG, bufAT, 0, BL, 0, 0,
        DG, 1, 0, nullptr, 0, 0, nullptr, 0, dinvR, 0);
    agg_packed<<<dim3(DG / 128, L / 128, BSZ), 256, 0, stream>>>(
        packedR, bufAT, BL, dinvR, bg_pro2, encB, mask_pro, bufY, L);
    mfma_gemm<0><<<dim3(L / 128, 1, KH * BSZ), 256, 0, stream>>>(
        WtBpro, (long long)DD * DG, DG, bufY, (long long)L * DG, DG,
        out + out_pro_off, (long long)DD * L, L, BSZ, 1,
        DG, KH, 1, bt_pro, 1, DD, nullptr, 0, nullptr, 1);
  }
}

// Round 5
// 512.855 us; speedup vs baseline: 4.4374x; 1.4525x over previous
//
#include <hip/hip_runtime.h>
#include <hip/hip_bf16.h>

// Problem constants
#define BSZ 16
#define LP 128
#define LR 1024
#define DD 128
#define DG 640
#define KH 7
#define SPLITK 4

typedef __bf16 bf16x8 __attribute__((ext_vector_type(8)));
typedef __bf16 bf16x4v __attribute__((ext_vector_type(4)));
typedef float f32x4 __attribute__((ext_vector_type(4)));
typedef unsigned int uint32;

// ---------------------------------------------------------------------------
// MFMA core: 128x128 tile, BK=64, 4 waves. C[m,n] = sum_k A[m,k]*Bt[n,k].
// AF32=1: A is f32, converted to bf16 during staging.
// ---------------------------------------------------------------------------
template <int AF32>
__device__ __forceinline__ void mfma_core(
    const void* __restrict__ A_, int lda,
    const ushort* __restrict__ Bb, int ldb,
    int m0, int n0, int kStart, int kEnd, f32x4 (&acc)[4][4]) {
  __shared__ __align__(16) ushort As[128 * 72];
  __shared__ __align__(16) ushort Bs[128 * 72];
  int t = threadIdx.x;
  int wave = t >> 6, lane = t & 63;
  int quad = lane >> 4, l16 = lane & 15;
  int wm = (wave >> 1) * 64, wn = (wave & 1) * 64;
  int r1 = t >> 2, o1 = (t & 3) * 16;

  for (int k0 = kStart; k0 < kEnd; k0 += 64) {
    int4 b00 = *(const int4*)(Bb + (size_t)(n0 + r1) * ldb + k0 + o1);
    int4 b01 = *(const int4*)(Bb + (size_t)(n0 + r1) * ldb + k0 + o1 + 8);
    int4 b10 = *(const int4*)(Bb + (size_t)(n0 + r1 + 64) * ldb + k0 + o1);
    int4 b11 = *(const int4*)(Bb + (size_t)(n0 + r1 + 64) * ldb + k0 + o1 + 8);
    int4 a00, a01, a10, a11;
    float4 af32[8];
    if (AF32) {
      const float* Af = (const float*)A_;
      #pragma unroll
      for (int s = 0; s < 8; ++s) {
        int idx = t + s * 256;
        int row = idx >> 4, c4 = (idx & 15) * 4;
        af32[s] = *(const float4*)(Af + (size_t)(m0 + row) * lda + k0 + c4);
      }
    } else {
      const ushort* Ab = (const ushort*)A_;
      a00 = *(const int4*)(Ab + (size_t)(m0 + r1) * lda + k0 + o1);
      a01 = *(const int4*)(Ab + (size_t)(m0 + r1) * lda + k0 + o1 + 8);
      a10 = *(const int4*)(Ab + (size_t)(m0 + r1 + 64) * lda + k0 + o1);
      a11 = *(const int4*)(Ab + (size_t)(m0 + r1 + 64) * lda + k0 + o1 + 8);
    }
    __syncthreads();
    if (AF32) {
      #pragma unroll
      for (int s = 0; s < 8; ++s) {
        int idx = t + s * 256;
        int row = idx >> 4, c4 = (idx & 15) * 4;
        ushort4 u; __bf16 h;
        h = (__bf16)af32[s].x; u.x = *(ushort*)&h;
        h = (__bf16)af32[s].y; u.y = *(ushort*)&h;
        h = (__bf16)af32[s].z; u.z = *(ushort*)&h;
        h = (__bf16)af32[s].w; u.w = *(ushort*)&h;
        *(ushort4*)&As[row * 72 + c4] = u;
      }
    } else {
      *(int4*)&As[r1 * 72 + o1] = a00;
      *(int4*)&As[r1 * 72 + o1 + 8] = a01;
      *(int4*)&As[(r1 + 64) * 72 + o1] = a10;
      *(int4*)&As[(r1 + 64) * 72 + o1 + 8] = a11;
    }
    *(int4*)&Bs[r1 * 72 + o1] = b00;
    *(int4*)&Bs[r1 * 72 + o1 + 8] = b01;
    *(int4*)&Bs[(r1 + 64) * 72 + o1] = b10;
    *(int4*)&Bs[(r1 + 64) * 72 + o1 + 8] = b11;
    __syncthreads();
    #pragma unroll
    for (int kc = 0; kc < 2; ++kc) {
      bf16x8 af[4], bfr[4];
      #pragma unroll
      for (int fi = 0; fi < 4; ++fi)
        af[fi] = *(const bf16x8*)&As[(wm + fi * 16 + l16) * 72 + kc * 32 + quad * 8];
      #pragma unroll
      for (int fj = 0; fj < 4; ++fj)
        bfr[fj] = *(const bf16x8*)&Bs[(wn + fj * 16 + l16) * 72 + kc * 32 + quad * 8];
      #pragma unroll
      for (int fi = 0; fi < 4; ++fi)
        #pragma unroll
        for (int fj = 0; fj < 4; ++fj)
          acc[fi][fj] = __builtin_amdgcn_mfma_f32_16x16x32_bf16(
              af[fi], bfr[fj], acc[fi][fj], 0, 0, 0);
    }
    __syncthreads();
  }
}

// ---------------------------------------------------------------------------
// agg core: A built in-register from packed adjacency bits, BK=64.
// acc[c][d] += sum_r Ahat[r,c] * Xt[d][bcol + r]
// ---------------------------------------------------------------------------
__device__ __forceinline__ void agg_core(
    const uint32* __restrict__ pb, int L,
    const ushort* __restrict__ Bb, int ldb,
    int m0, int n0, f32x4 (&acc)[4][4]) {
  __shared__ __align__(16) ushort Bs[128 * 72];
  __shared__ uint32 Aw[2][128];
  int t = threadIdx.x;
  int wave = t >> 6, lane = t & 63;
  int quad = lane >> 4, l16 = lane & 15;
  int wm = (wave >> 1) * 64, wn = (wave & 1) * 64;
  int r1 = t >> 2, o1 = (t & 3) * 16;
  int half = t >> 7, cc = t & 127;

  for (int k0 = 0; k0 < L; k0 += 64) {
    int4 b00 = *(const int4*)(Bb + (size_t)(n0 + r1) * ldb + k0 + o1);
    int4 b01 = *(const int4*)(Bb + (size_t)(n0 + r1) * ldb + k0 + o1 + 8);
    int4 b10 = *(const int4*)(Bb + (size_t)(n0 + r1 + 64) * ldb + k0 + o1);
    int4 b11 = *(const int4*)(Bb + (size_t)(n0 + r1 + 64) * ldb + k0 + o1 + 8);
    uint32 w = pb[(size_t)((k0 >> 5) + half) * L + m0 + cc];
    __syncthreads();
    *(int4*)&Bs[r1 * 72 + o1] = b00;
    *(int4*)&Bs[r1 * 72 + o1 + 8] = b01;
    *(int4*)&Bs[(r1 + 64) * 72 + o1] = b10;
    *(int4*)&Bs[(r1 + 64) * 72 + o1 + 8] = b11;
    Aw[half][cc] = w;
    __syncthreads();
    #pragma unroll
    for (int kc = 0; kc < 2; ++kc) {
      bf16x8 af[4], bfr[4];
      #pragma unroll
      for (int fj = 0; fj < 4; ++fj)
        bfr[fj] = *(const bf16x8*)&Bs[(wn + fj * 16 + l16) * 72 + kc * 32 + quad * 8];
      #pragma unroll
      for (int fi = 0; fi < 4; ++fi) {
        uint32 bits = (Aw[kc][wm + fi * 16 + l16] >> (quad * 8)) & 0xffu;
        int4 p;
        p.x = (int)((((bits >> 0) & 1) ? 0x3F80u : 0u) | (((bits >> 1) & 1) ? 0x3F800000u : 0u));
        p.y = (int)((((bits >> 2) & 1) ? 0x3F80u : 0u) | (((bits >> 3) & 1) ? 0x3F800000u : 0u));
        p.z = (int)((((bits >> 4) & 1) ? 0x3F80u : 0u) | (((bits >> 5) & 1) ? 0x3F800000u : 0u));
        p.w = (int)((((bits >> 6) & 1) ? 0x3F80u : 0u) | (((bits >> 7) & 1) ? 0x3F800000u : 0u));
        af[fi] = *(bf16x8*)&p;
      }
      #pragma unroll
      for (int fi = 0; fi < 4; ++fi)
        #pragma unroll
        for (int fj = 0; fj < 4; ++fj)
          acc[fi][fj] = __builtin_amdgcn_mfma_f32_16x16x32_bf16(
              af[fi], bfr[fj], acc[fi][fj], 0, 0, 0);
    }
    __syncthreads();
  }
}

// ---------------------------------------------------------------------------
// prep_weights: all weight conversions/transposes in one dispatch.
// grid (560, 1, 8)
// ---------------------------------------------------------------------------
__device__ __forceinline__ void tr_tile(const float* __restrict__ src,
                                        __bf16* __restrict__ dst,
                                        int R, int C, int cb, int rb, int t) {
  __shared__ float T[32][33];
  int r0 = rb * 32, c0 = cb * 32;
  #pragma unroll
  for (int s = 0; s < 4; ++s) {
    int idx = t + s * 256;
    int r = idx >> 5, c = idx & 31;
    T[r][c] = src[(size_t)(r0 + r) * C + c0 + c];
  }
  __syncthreads();
  #pragma unroll
  for (int s = 0; s < 4; ++s) {
    int idx = t + s * 256;
    int c = idx >> 5, r = idx & 31;
    dst[(size_t)(c0 + c) * R + r0 + r] = (__bf16)T[r][c];
  }
}

__global__ __launch_bounds__(256) void prep_weights(
    const float* __restrict__ Wppep, const float* __restrict__ Wppro,
    const float* __restrict__ Wg1p, const float* __restrict__ Wg2p,
    const float* __restrict__ Wg1r, const float* __restrict__ Wg2r,
    const float* __restrict__ Wtp, const float* __restrict__ Wtr,
    __bf16* __restrict__ WppTp, __bf16* __restrict__ WppTr,
    __bf16* __restrict__ Wg1Tp, __bf16* __restrict__ Wg2Tp,
    __bf16* __restrict__ Wg1Tr, __bf16* __restrict__ Wg2Tr,
    __bf16* __restrict__ WtBp, __bf16* __restrict__ WtBr) {
  int z = blockIdx.z, bx = blockIdx.x, t = threadIdx.x;
  if (z < 2) {
    if (bx >= 128) return;
    tr_tile(z ? Wppro : Wppep, z ? WppTr : WppTp, 1024, 128, bx % 4, bx / 4, t);
  } else if (z < 6) {
    if (bx >= 400) return;
    const float* src = (z == 2) ? Wg1p : (z == 3) ? Wg2p : (z == 4) ? Wg1r : Wg2r;
    __bf16* dst = (z == 2) ? Wg1Tp : (z == 3) ? Wg2Tp : (z == 4) ? Wg1Tr : Wg2Tr;
    tr_tile(src, dst, 640, 640, bx % 20, bx / 20, t);
  } else {
    if (bx >= 560) return;
    const float* src = (z == 6) ? Wtp : Wtr;
    __bf16* dst = (z == 6) ? WtBp : WtBr;
    int i = bx * 256 + t;  // < 143360 float4s
    float4 v = ((const float4*)src)[i];
    bf16x4v o;
    o.x = (__bf16)v.x; o.y = (__bf16)v.y; o.z = (__bf16)v.z; o.w = (__bf16)v.w;
    ((bf16x4v*)dst)[i] = o;
  }
}

// ---------------------------------------------------------------------------
// Utility
// ---------------------------------------------------------------------------
__global__ __launch_bounds__(256) void zero_f32(float* __restrict__ p, int n) {
  int i = blockIdx.x * 256 + threadIdx.x;
  if (i < n) p[i] = 0.f;
}

__global__ __launch_bounds__(256) void rsqrt_k(const float* __restrict__ deg,
                                               float* __restrict__ dinv, int n) {
  int i = blockIdx.x * 256 + threadIdx.x;
  if (i < n) dinv[i] = rsqrtf(deg[i]);
}

// ---------------------------------------------------------------------------
// prep_pack merged: grid (4, 32, 17). z<16: pro (b=z, rw=y, c=x*256+t);
// z==16: pep (b=y<16, rw=x, c=t<128).
// ---------------------------------------------------------------------------
__global__ __launch_bounds__(256) void prep_pack_merged(
    const float* __restrict__ adjP, const float* __restrict__ adjR,
    uint32* __restrict__ packedP, uint32* __restrict__ packedR,
    float* __restrict__ degP, float* __restrict__ degR) {
  int t = threadIdx.x;
  const float* adj; uint32* packed; float* deg;
  int b, rw, c, L;
  if (blockIdx.z < 16) {
    L = LR; b = blockIdx.z; rw = blockIdx.y; c = blockIdx.x * 256 + t;
    adj = adjR; packed = packedR; deg = degR;
  } else {
    L = LP; b = blockIdx.y; rw = blockIdx.x; c = t;
    if (b >= 16 || c >= LP) return;
    adj = adjP; packed = packedP; deg = degP;
  }
  const float* adjB = adj + (size_t)b * L * L;
  uint32 w = 0;
  int rbase = rw * 32;
  #pragma unroll 8
  for (int j = 0; j < 32; ++j) {
    float a = adjB[(size_t)(rbase + j) * L + c];
    if (a != 0.f || (rbase + j) == c) w |= (1u << j);
  }
  packed[((size_t)b * (L >> 5) + rw) * L + c] = w;
  atomicAdd(deg + b * L + c, (float)__popc(w));
}

// ---------------------------------------------------------------------------
// pre_gemm merged (split-K pretrain partials): grid (144, SPLITK).
// bx<16: pep m-block bx; else pro m-block bx-16. by = k-slice.
// part[s][m][n] f32 raw.
// ---------------------------------------------------------------------------
__global__ __launch_bounds__(256) void pre_gemm(
    const float* __restrict__ XpP, const float* __restrict__ XpR,
    const __bf16* __restrict__ WppTp, const __bf16* __restrict__ WppTr,
    float* __restrict__ partP, float* __restrict__ partR) {
  int bx = blockIdx.x, s = blockIdx.y;
  int pep = bx < (BSZ * LP / 128);
  int m0 = (pep ? bx : bx - BSZ * LP / 128) * 128;
  const float* A = pep ? XpP : XpR;
  const ushort* B = (const ushort*)(pep ? WppTp : WppTr);
  int BL = pep ? BSZ * LP : BSZ * LR;
  float* part = (pep ? partP : partR) + (size_t)s * BL * DD;

  f32x4 acc[4][4];
  #pragma unroll
  for (int i = 0; i < 4; ++i)
    #pragma unroll
    for (int j = 0; j < 4; ++j) acc[i][j] = (f32x4){0.f, 0.f, 0.f, 0.f};
  mfma_core<1>(A, 1024, B, 1024, m0, 0, s * (1024 / SPLITK),
               (s + 1) * (1024 / SPLITK), acc);

  int t = threadIdx.x;
  int wave = t >> 6, lane = t & 63;
  int quad = lane >> 4, l16 = lane & 15;
  int wm = (wave >> 1) * 64, wn = (wave & 1) * 64;
  #pragma unroll
  for (int fi = 0; fi < 4; ++fi)
    #pragma unroll
    for (int r = 0; r < 4; ++r) {
      int m = m0 + wm + fi * 16 + quad * 4 + r;
      #pragma unroll
      for (int fj = 0; fj < 4; ++fj) {
        int n = wn + fj * 16 + l16;
        part[(size_t)m * DD + n] = acc[fi][fj][r];
      }
    }
}

// ---------------------------------------------------------------------------
// Encoder merged: embeddings + dense matmul + pretrain-partial reduce.
// grid (BLp + BLr, 128 threads)
// ---------------------------------------------------------------------------
__global__ __launch_bounds__(128) void encoder_merged(
    const int* __restrict__ xsP, const int* __restrict__ xssP,
    const int* __restrict__ x2P, const float* __restrict__ xdP,
    const float* __restrict__ WdP, const float* __restrict__ bdP,
    const float* __restrict__ maskP, const float* __restrict__ partP,
    const float* __restrict__ bppP, __bf16* __restrict__ encP,
    const int* __restrict__ xsR, const int* __restrict__ xssR,
    const int* __restrict__ x2R, const float* __restrict__ xdR,
    const float* __restrict__ WdR, const float* __restrict__ bdR,
    const float* __restrict__ maskR, const float* __restrict__ partR,
    const float* __restrict__ bppR, __bf16* __restrict__ encR,
    const float* __restrict__ Eseq, const float* __restrict__ Ess,
    const float* __restrict__ Etwo) {
  int gw = blockIdx.x;
  int t = threadIdx.x;
  int pep = gw < BSZ * LP;
  int row = pep ? gw : gw - BSZ * LP;
  int BL = pep ? BSZ * LP : BSZ * LR;
  int Kd = pep ? 3 : 23;
  const int* xs = pep ? xsP : xsR;
  const int* xss = pep ? xssP : xssR;
  const int* x2 = pep ? x2P : x2R;
  const float* xd = pep ? xdP : xdR;
  const float* Wd = pep ? WdP : WdR;
  const float* bd = pep ? bdP : bdR;
  const float* mask = pep ? maskP : maskR;
  const float* part = pep ? partP : partR;
  const float* bpp = pep ? bppP : bppR;
  __bf16* enc = pep ? encP : encR;

  float m = mask[row];
  int i0 = xs[row], i1 = xss[row], i2 = x2[row];
  __bf16* e = enc + (size_t)row * DG;
  e[t]        = (__bf16)(Eseq[i0 * DD + t] * m);
  e[DD + t]   = (__bf16)(Ess[i1 * DD + t] * m);
  e[2*DD + t] = (__bf16)(Etwo[i2 * DD + t] * m);
  float acc = bd[t];
  const float* xr = xd + (size_t)row * Kd;
  for (int i = 0; i < Kd; ++i) acc = fmaf(xr[i], Wd[i * DD + t], acc);
  e[3*DD + t] = (__bf16)(acc * m);
  // pretrain reduce -> cols 512..639
  float p = bpp[t];
  #pragma unroll
  for (int s = 0; s < SPLITK; ++s)
    p += part[(size_t)s * BL * DD + (size_t)row * DD + t];
  e[4*DD + t] = (__bf16)(p * m);
}

// ---------------------------------------------------------------------------
// linT merged: bufAT[d][row] = dinv[row] * sum_k src[row][k] * Wg[k][d]
// grid (144, 5): bx<16 pep n-block, else pro. by = m-block (d).
// ---------------------------------------------------------------------------
__global__ __launch_bounds__(256) void linT_merged(
    const __bf16* __restrict__ WgTp, const __bf16* __restrict__ srcP,
    const float* __restrict__ dinvP, __bf16* __restrict__ dstP,
    const __bf16* __restrict__ WgTr, const __bf16* __restrict__ srcR,
    const float* __restrict__ dinvR, __bf16* __restrict__ dstR) {
  int bx = blockIdx.x;
  int pep = bx < (BSZ * LP / 128);
  int n0 = (pep ? bx : bx - BSZ * LP / 128) * 128;
  int m0 = blockIdx.y * 128;
  int BL = pep ? BSZ * LP : BSZ * LR;
  const __bf16* A = pep ? WgTp : WgTr;
  const ushort* B = (const ushort*)(pep ? srcP : srcR);
  const float* dinv = pep ? dinvP : dinvR;
  __bf16* dst = pep ? dstP : dstR;

  f32x4 acc[4][4];
  #pragma unroll
  for (int i = 0; i < 4; ++i)
    #pragma unroll
    for (int j = 0; j < 4; ++j) acc[i][j] = (f32x4){0.f, 0.f, 0.f, 0.f};
  mfma_core<0>(A, DG, B, DG, m0, n0, 0, DG, acc);

  int t = threadIdx.x;
  int wave = t >> 6, lane = t & 63;
  int quad = lane >> 4, l16 = lane & 15;
  int wm = (wave >> 1) * 64, wn = (wave & 1) * 64;
  #pragma unroll
  for (int fi = 0; fi < 4; ++fi)
    #pragma unroll
    for (int r = 0; r < 4; ++r) {
      int m = m0 + wm + fi * 16 + quad * 4 + r;
      #pragma unroll
      for (int fj = 0; fj < 4; ++fj) {
        int n = n0 + wn + fj * 16 + l16;
        dst[(size_t)m * BL + n] = (__bf16)(acc[fi][fj][r] * dinv[n]);
      }
    }
}

// ---------------------------------------------------------------------------
// agg merged: grid (5, 9, 16). by==0: pep (m0=0); else pro m-block by-1.
// Y[b,c,d] = relu(dinv*acc + bias[d] (+encE)) * (mask?)
// ---------------------------------------------------------------------------
__global__ __launch_bounds__(256) void agg_merged(
    const uint32* __restrict__ packedP, const __bf16* __restrict__ XtP,
    const float* __restrict__ dinvP, const float* __restrict__ biasP,
    const __bf16* __restrict__ encEP, const float* __restrict__ maskP,
    __bf16* __restrict__ YP,
    const uint32* __restrict__ packedR, const __bf16* __restrict__ XtR,
    const float* __restrict__ dinvR, const float* __restrict__ biasR,
    const __bf16* __restrict__ encER, const float* __restrict__ maskR,
    __bf16* __restrict__ YR) {
  int b = blockIdx.z;
  int pep = (blockIdx.y == 0);
  int L = pep ? LP : LR;
  int BL = BSZ * L;
  int m0 = pep ? 0 : (blockIdx.y - 1) * 128;
  int n0 = blockIdx.x * 128;
  const uint32* pb = (pep ? packedP : packedR) + (size_t)b * (L >> 5) * L;
  const ushort* Bb = (const ushort*)(pep ? XtP : XtR) + (size_t)b * L;
  const float* dinv = pep ? dinvP : dinvR;
  const float* bias = pep ? biasP : biasR;
  const __bf16* encE = pep ? encEP : encER;
  const float* mask = pep ? maskP : maskR;
  __bf16* Y = pep ? YP : YR;

  f32x4 acc[4][4];
  #pragma unroll
  for (int i = 0; i < 4; ++i)
    #pragma unroll
    for (int j = 0; j < 4; ++j) acc[i][j] = (f32x4){0.f, 0.f, 0.f, 0.f};
  agg_core(pb, L, Bb, BL, m0, n0, acc);

  int t = threadIdx.x;
  int wave = t >> 6, lane = t & 63;
  int quad = lane >> 4, l16 = lane & 15;
  int wm = (wave >> 1) * 64, wn = (wave & 1) * 64;
  int gRow = b * L;
  #pragma unroll
  for (int fi = 0; fi < 4; ++fi)
    #pragma unroll
    for (int r = 0; r < 4; ++r) {
      int m = m0 + wm + fi * 16 + quad * 4 + r;
      int gi = gRow + m;
      float di = dinv[gi];
      float rm = mask ? mask[gi] : 1.f;
      #pragma unroll
      for (int fj = 0; fj < 4; ++fj) {
        int n = n0 + wn + fj * 16 + l16;
        float v = acc[fi][fj][r] * di + bias[n];
        if (encE) v += (float)encE[(size_t)gi * DG + n];
        v = fmaxf(v, 0.f);
        v *= rm;
        Y[(size_t)gi * DG + n] = (__bf16)v;
      }
    }
}

// ---------------------------------------------------------------------------
// fct merged: grid (8, 7, 18). bz<16: pro (b=bz, n over L); bz>=16: pep
// (n over BL flattened, b=n>>7). out f32.
// ---------------------------------------------------------------------------
__global__ __launch_bounds__(256) void fct_merged(
    const __bf16* __restrict__ WtBp, const float* __restrict__ btp,
    const __bf16* __restrict__ Yp, float* __restrict__ outP,
    const __bf16* __restrict__ WtBr, const float* __restrict__ btr,
    const __bf16* __restrict__ Yr, float* __restrict__ outR) {
  int kh = blockIdx.y;
  int pro = (blockIdx.z < 16);
  const __bf16* A;
  const ushort* B;
  const float* bt;
  int n0;
  if (pro) {
    A = WtBr + (size_t)kh * DD * DG;
    B = (const ushort*)(Yr + (size_t)blockIdx.z * LR * DG);
    bt = btr;
    n0 = blockIdx.x * 128;
  } else {
    A = WtBp + (size_t)kh * DD * DG;
    B = (const ushort*)Yp;
    bt = btp;
    n0 = ((blockIdx.z - 16) * 8 + blockIdx.x) * 128;
  }

  f32x4 acc[4][4];
  #pragma unroll
  for (int i = 0; i < 4; ++i)
    #pragma unroll
    for (int j = 0; j < 4; ++j) acc[i][j] = (f32x4){0.f, 0.f, 0.f, 0.f};
  mfma_core<0>(A, DG, B, DG, 0, n0, 0, DG, acc);

  int t = threadIdx.x;
  int wave = t >> 6, lane = t & 63;
  int quad = lane >> 4, l16 = lane & 15;
  int wm = (wave >> 1) * 64, wn = (wave & 1) * 64;
  #pragma unroll
  for (int fi = 0; fi < 4; ++fi)
    #pragma unroll
    for (int r = 0; r < 4; ++r) {
      int m = wm + fi * 16 + quad * 4 + r;
      float bb = bt[kh * DD + m];
      #pragma unroll
      for (int fj = 0; fj < 4; ++fj) {
        int n = n0 + wn + fj * 16 + l16;
        float v = fmaxf(acc[fi][fj][r] + bb, 0.f);
        if (pro) {
          outR[((size_t)(kh * BSZ + blockIdx.z) * DD + m) * LR + n] = v;
        } else {
          int b = n >> 7, l = n & 127;
          outP[((size_t)(kh * BSZ + b) * DD + m) * LP + l] = v;
        }
      }
    }
}

// ---------------------------------------------------------------------------
extern "C" void kernel_launch(void* const* d_in, const int* in_sizes, int n_in,
                              void* d_out, int out_size, void* d_ws, size_t ws_size,
                              hipStream_t stream) {
  const int*   x_pep          = (const int*)d_in[0];
  const int*   x_ss_pep       = (const int*)d_in[1];
  const int*   x_2_pep        = (const int*)d_in[2];
  const float* x_dense_pep    = (const float*)d_in[3];
  const float* x_pretrain_pep = (const float*)d_in[4];
  const int*   x_pro          = (const int*)d_in[5];
  const int*   x_ss_pro       = (const int*)d_in[6];
  const int*   x_2_pro        = (const int*)d_in[7];
  const float* x_dense_pro    = (const float*)d_in[8];
  const float* x_pretrain_pro = (const float*)d_in[9];
  const float* x_edge_pep     = (const float*)d_in[10];
  const float* x_edge_pro     = (const float*)d_in[11];
  const float* mask_pep       = (const float*)d_in[12];
  const float* mask_pro       = (const float*)d_in[13];
  const float* E_seq          = (const float*)d_in[14];
  const float* E_ss           = (const float*)d_in[15];
  const float* E_two          = (const float*)d_in[16];
  const float* W_dpep         = (const float*)d_in[17];
  const float* b_dpep         = (const float*)d_in[18];
  const float* W_dpro         = (const float*)d_in[19];
  const float* b_dpro         = (const float*)d_in[20];
  const float* W_ppep         = (const float*)d_in[21];
  const float* b_ppep         = (const float*)d_in[22];
  const float* W_ppro         = (const float*)d_in[23];
  const float* b_ppro         = (const float*)d_in[24];
  const float* Wg_pep1        = (const float*)d_in[25];
  const float* bg_pep1        = (const float*)d_in[26];
  const float* Wg_pep2        = (const float*)d_in[27];
  const float* bg_pep2        = (const float*)d_in[28];
  const float* Wg_pro1        = (const float*)d_in[29];
  const float* bg_pro1        = (const float*)d_in[30];
  const float* Wg_pro2        = (const float*)d_in[31];
  const float* bg_pro2        = (const float*)d_in[32];
  const float* Wt_pep         = (const float*)d_in[33];
  const float* bt_pep         = (const float*)d_in[34];
  const float* Wt_pro         = (const float*)d_in[35];
  const float* bt_pro         = (const float*)d_in[36];

  float* out = (float*)d_out;
  const int BLp = BSZ * LP;   // 2048
  const int BLr = BSZ * LR;   // 16384
  const size_t out_pro_off = (size_t)KH * BSZ * DD * LP;

  // Workspace layout (~117 MB)
  char* w = (char*)d_ws;
  __bf16* encBp  = (__bf16*)w; w += (size_t)BLp * DG * 2;
  __bf16* encBr  = (__bf16*)w; w += (size_t)BLr * DG * 2;
  __bf16* bufATp = (__bf16*)w; w += (size_t)DG * BLp * 2;
  __bf16* bufATr = (__bf16*)w; w += (size_t)DG * BLr * 2;
  __bf16* bufYp  = (__bf16*)w; w += (size_t)BLp * DG * 2;
  __bf16* bufYr  = (__bf16*)w; w += (size_t)BLr * DG * 2;
  __bf16* WppTp  = (__bf16*)w; w += (size_t)DD * 1024 * 2;
  __bf16* WppTr  = (__bf16*)w; w += (size_t)DD * 1024 * 2;
  __bf16* Wg1Tp  = (__bf16*)w; w += (size_t)DG * DG * 2;
  __bf16* Wg2Tp  = (__bf16*)w; w += (size_t)DG * DG * 2;
  __bf16* Wg1Tr  = (__bf16*)w; w += (size_t)DG * DG * 2;
  __bf16* Wg2Tr  = (__bf16*)w; w += (size_t)DG * DG * 2;
  __bf16* WtBp   = (__bf16*)w; w += (size_t)KH * DD * DG * 2;
  __bf16* WtBr   = (__bf16*)w; w += (size_t)KH * DD * DG * 2;
  uint32* packedP = (uint32*)w; w += (size_t)BSZ * (LP / 32) * LP * 4;
  uint32* packedR = (uint32*)w; w += (size_t)BSZ * (LR / 32) * LR * 4;
  float* degP  = (float*)w; w += (size_t)BLp * 4;
  float* degR  = (float*)w; w += (size_t)BLr * 4;
  float* dinvP = (float*)w; w += (size_t)BLp * 4;
  float* dinvR = (float*)w; w += (size_t)BLr * 4;
  float* partP = (float*)w; w += (size_t)SPLITK * BLp * DD * 4;
  float* partR = (float*)w; w += (size_t)SPLITK * BLr * DD * 4;

  // 1. weights
  prep_weights<<<dim3(560, 1, 8), 256, 0, stream>>>(
      W_ppep, W_ppro, Wg_pep1, Wg_pep2, Wg_pro1, Wg_pro2, Wt_pep, Wt_pro,
      WppTp, WppTr, Wg1Tp, Wg2Tp, Wg1Tr, Wg2Tr, WtBp, WtBr);
  // 2-4. adjacency prep (degP,degR contiguous; dinvP,dinvR contiguous)
  zero_f32<<<(BLp + BLr) / 256, 256, 0, stream>>>(degP, BLp + BLr);
  prep_pack_merged<<<dim3(4, 32, 17), 256, 0, stream>>>(
      x_edge_pep, x_edge_pro, packedP, packedR, degP, degR);
  rsqrt_k<<<(BLp + BLr) / 256, 256, 0, stream>>>(degP, dinvP, BLp + BLr);
  // 5. pretrain split-K partials
  pre_gemm<<<dim3((BLp + BLr) / 128, SPLITK), 256, 0, stream>>>(
      x_pretrain_pep, x_pretrain_pro, WppTp, WppTr, partP, partR);
  // 6. encoder (+ pretrain reduce)
  encoder_merged<<<BLp + BLr, 128, 0, stream>>>(
      x_pep, x_ss_pep, x_2_pep, x_dense_pep, W_dpep, b_dpep, mask_pep, partP,
      b_ppep, encBp,
      x_pro, x_ss_pro, x_2_pro, x_dense_pro, W_dpro, b_dpro, mask_pro, partR,
      b_ppro, encBr,
      E_seq, E_ss, E_two);
  // 7-10. GCN
  linT_merged<<<dim3((BLp + BLr) / 128, DG / 128), 256, 0, stream>>>(
      Wg1Tp, encBp, dinvP, bufATp, Wg1Tr, encBr, dinvR, bufATr);
  agg_merged<<<dim3(DG / 128, 1 + LR / 128, BSZ), 256, 0, stream>>>(
      packedP, bufATp, dinvP, bg_pep1, nullptr, nullptr, bufYp,
      packedR, bufATr, dinvR, bg_pro1, nullptr, nullptr, bufYr);
  linT_merged<<<dim3((BLp + BLr) / 128, DG / 128), 256, 0, stream>>>(
      Wg2Tp, bufYp, dinvP, bufATp, Wg2Tr, bufYr, dinvR, bufATr);
  agg_merged<<<dim3(DG / 128, 1 + LR / 128, BSZ), 256, 0, stream>>>(
      packedP, bufATp, dinvP, bg_pep2, encBp, mask_pep, bufYp,
      packedR, bufATr, dinvR, bg_pro2, encBr, mask_pro, bufYr);
  // 11. fct
  fct_merged<<<dim3(LR / 128, KH, 18), 256, 0, stream>>>(
      WtBp, bt_pep, bufYp, out,
      WtBr, bt_pro, bufYr, out + out_pro_off);
}

// Round 6
// 503.250 us; speedup vs baseline: 4.5221x; 1.0191x over previous
//
#include <hip/hip_runtime.h>
#include <hip/hip_bf16.h>

// Problem constants
#define BSZ 16
#define LP 128
#define LR 1024
#define DD 128
#define DG 640
#define KH 7
#define SPLITK 4

typedef __bf16 bf16x8 __attribute__((ext_vector_type(8)));
typedef __bf16 bf16x4v __attribute__((ext_vector_type(4)));
typedef float f32x4 __attribute__((ext_vector_type(4)));
typedef unsigned int uint32;

// ---------------------------------------------------------------------------
// MFMA core: 128x128 tile, BK=64, 4 waves. C[m,n] = sum_k A[m,k]*Bt[n,k].
// AF32=1: A is f32, converted to bf16 during staging.
// ---------------------------------------------------------------------------
template <int AF32>
__device__ __forceinline__ void mfma_core(
    const void* __restrict__ A_, int lda,
    const ushort* __restrict__ Bb, int ldb,
    int m0, int n0, int kStart, int kEnd, f32x4 (&acc)[4][4]) {
  __shared__ __align__(16) ushort As[128 * 72];
  __shared__ __align__(16) ushort Bs[128 * 72];
  int t = threadIdx.x;
  int wave = t >> 6, lane = t & 63;
  int quad = lane >> 4, l16 = lane & 15;
  int wm = (wave >> 1) * 64, wn = (wave & 1) * 64;
  int r1 = t >> 2, o1 = (t & 3) * 16;

  for (int k0 = kStart; k0 < kEnd; k0 += 64) {
    int4 b00 = *(const int4*)(Bb + (size_t)(n0 + r1) * ldb + k0 + o1);
    int4 b01 = *(const int4*)(Bb + (size_t)(n0 + r1) * ldb + k0 + o1 + 8);
    int4 b10 = *(const int4*)(Bb + (size_t)(n0 + r1 + 64) * ldb + k0 + o1);
    int4 b11 = *(const int4*)(Bb + (size_t)(n0 + r1 + 64) * ldb + k0 + o1 + 8);
    int4 a00, a01, a10, a11;
    float4 af32[8];
    if (AF32) {
      const float* Af = (const float*)A_;
      #pragma unroll
      for (int s = 0; s < 8; ++s) {
        int idx = t + s * 256;
        int row = idx >> 4, c4 = (idx & 15) * 4;
        af32[s] = *(const float4*)(Af + (size_t)(m0 + row) * lda + k0 + c4);
      }
    } else {
      const ushort* Ab = (const ushort*)A_;
      a00 = *(const int4*)(Ab + (size_t)(m0 + r1) * lda + k0 + o1);
      a01 = *(const int4*)(Ab + (size_t)(m0 + r1) * lda + k0 + o1 + 8);
      a10 = *(const int4*)(Ab + (size_t)(m0 + r1 + 64) * lda + k0 + o1);
      a11 = *(const int4*)(Ab + (size_t)(m0 + r1 + 64) * lda + k0 + o1 + 8);
    }
    __syncthreads();
    if (AF32) {
      #pragma unroll
      for (int s = 0; s < 8; ++s) {
        int idx = t + s * 256;
        int row = idx >> 4, c4 = (idx & 15) * 4;
        ushort4 u; __bf16 h;
        h = (__bf16)af32[s].x; u.x = *(ushort*)&h;
        h = (__bf16)af32[s].y; u.y = *(ushort*)&h;
        h = (__bf16)af32[s].z; u.z = *(ushort*)&h;
        h = (__bf16)af32[s].w; u.w = *(ushort*)&h;
        *(ushort4*)&As[row * 72 + c4] = u;
      }
    } else {
      *(int4*)&As[r1 * 72 + o1] = a00;
      *(int4*)&As[r1 * 72 + o1 + 8] = a01;
      *(int4*)&As[(r1 + 64) * 72 + o1] = a10;
      *(int4*)&As[(r1 + 64) * 72 + o1 + 8] = a11;
    }
    *(int4*)&Bs[r1 * 72 + o1] = b00;
    *(int4*)&Bs[r1 * 72 + o1 + 8] = b01;
    *(int4*)&Bs[(r1 + 64) * 72 + o1] = b10;
    *(int4*)&Bs[(r1 + 64) * 72 + o1 + 8] = b11;
    __syncthreads();
    #pragma unroll
    for (int kc = 0; kc < 2; ++kc) {
      bf16x8 af[4], bfr[4];
      #pragma unroll
      for (int fi = 0; fi < 4; ++fi)
        af[fi] = *(const bf16x8*)&As[(wm + fi * 16 + l16) * 72 + kc * 32 + quad * 8];
      #pragma unroll
      for (int fj = 0; fj < 4; ++fj)
        bfr[fj] = *(const bf16x8*)&Bs[(wn + fj * 16 + l16) * 72 + kc * 32 + quad * 8];
      #pragma unroll
      for (int fi = 0; fi < 4; ++fi)
        #pragma unroll
        for (int fj = 0; fj < 4; ++fj)
          acc[fi][fj] = __builtin_amdgcn_mfma_f32_16x16x32_bf16(
              af[fi], bfr[fj], acc[fi][fj], 0, 0, 0);
    }
    __syncthreads();
  }
}

// ---------------------------------------------------------------------------
// agg core: A built in-register from packed adjacency bits, BK=64.
// acc[c][d] += sum_r Ahat[r,c] * Xt[d][bcol + r]
// ---------------------------------------------------------------------------
__device__ __forceinline__ void agg_core(
    const uint32* __restrict__ pb, int L,
    const ushort* __restrict__ Bb, int ldb,
    int m0, int n0, f32x4 (&acc)[4][4]) {
  __shared__ __align__(16) ushort Bs[128 * 72];
  __shared__ uint32 Aw[2][128];
  int t = threadIdx.x;
  int wave = t >> 6, lane = t & 63;
  int quad = lane >> 4, l16 = lane & 15;
  int wm = (wave >> 1) * 64, wn = (wave & 1) * 64;
  int r1 = t >> 2, o1 = (t & 3) * 16;
  int half = t >> 7, cc = t & 127;

  for (int k0 = 0; k0 < L; k0 += 64) {
    int4 b00 = *(const int4*)(Bb + (size_t)(n0 + r1) * ldb + k0 + o1);
    int4 b01 = *(const int4*)(Bb + (size_t)(n0 + r1) * ldb + k0 + o1 + 8);
    int4 b10 = *(const int4*)(Bb + (size_t)(n0 + r1 + 64) * ldb + k0 + o1);
    int4 b11 = *(const int4*)(Bb + (size_t)(n0 + r1 + 64) * ldb + k0 + o1 + 8);
    uint32 w = pb[(size_t)((k0 >> 5) + half) * L + m0 + cc];
    __syncthreads();
    *(int4*)&Bs[r1 * 72 + o1] = b00;
    *(int4*)&Bs[r1 * 72 + o1 + 8] = b01;
    *(int4*)&Bs[(r1 + 64) * 72 + o1] = b10;
    *(int4*)&Bs[(r1 + 64) * 72 + o1 + 8] = b11;
    Aw[half][cc] = w;
    __syncthreads();
    #pragma unroll
    for (int kc = 0; kc < 2; ++kc) {
      bf16x8 af[4], bfr[4];
      #pragma unroll
      for (int fj = 0; fj < 4; ++fj)
        bfr[fj] = *(const bf16x8*)&Bs[(wn + fj * 16 + l16) * 72 + kc * 32 + quad * 8];
      #pragma unroll
      for (int fi = 0; fi < 4; ++fi) {
        uint32 bits = (Aw[kc][wm + fi * 16 + l16] >> (quad * 8)) & 0xffu;
        int4 p;
        p.x = (int)((((bits >> 0) & 1) ? 0x3F80u : 0u) | (((bits >> 1) & 1) ? 0x3F800000u : 0u));
        p.y = (int)((((bits >> 2) & 1) ? 0x3F80u : 0u) | (((bits >> 3) & 1) ? 0x3F800000u : 0u));
        p.z = (int)((((bits >> 4) & 1) ? 0x3F80u : 0u) | (((bits >> 5) & 1) ? 0x3F800000u : 0u));
        p.w = (int)((((bits >> 6) & 1) ? 0x3F80u : 0u) | (((bits >> 7) & 1) ? 0x3F800000u : 0u));
        af[fi] = *(bf16x8*)&p;
      }
      #pragma unroll
      for (int fi = 0; fi < 4; ++fi)
        #pragma unroll
        for (int fj = 0; fj < 4; ++fj)
          acc[fi][fj] = __builtin_amdgcn_mfma_f32_16x16x32_bf16(
              af[fi], bfr[fj], acc[fi][fj], 0, 0, 0);
    }
    __syncthreads();
  }
}

// ---------------------------------------------------------------------------
// prep_weights: all weight conversions/transposes in one dispatch.
// grid (560, 1, 8)
// ---------------------------------------------------------------------------
__device__ __forceinline__ void tr_tile(const float* __restrict__ src,
                                        __bf16* __restrict__ dst,
                                        int R, int C, int cb, int rb, int t) {
  __shared__ float T[32][33];
  int r0 = rb * 32, c0 = cb * 32;
  #pragma unroll
  for (int s = 0; s < 4; ++s) {
    int idx = t + s * 256;
    int r = idx >> 5, c = idx & 31;
    T[r][c] = src[(size_t)(r0 + r) * C + c0 + c];
  }
  __syncthreads();
  #pragma unroll
  for (int s = 0; s < 4; ++s) {
    int idx = t + s * 256;
    int c = idx >> 5, r = idx & 31;
    dst[(size_t)(c0 + c) * R + r0 + r] = (__bf16)T[r][c];
  }
}

__global__ __launch_bounds__(256) void prep_weights(
    const float* __restrict__ Wppep, const float* __restrict__ Wppro,
    const float* __restrict__ Wg1p, const float* __restrict__ Wg2p,
    const float* __restrict__ Wg1r, const float* __restrict__ Wg2r,
    const float* __restrict__ Wtp, const float* __restrict__ Wtr,
    __bf16* __restrict__ WppTp, __bf16* __restrict__ WppTr,
    __bf16* __restrict__ Wg1Tp, __bf16* __restrict__ Wg2Tp,
    __bf16* __restrict__ Wg1Tr, __bf16* __restrict__ Wg2Tr,
    __bf16* __restrict__ WtBp, __bf16* __restrict__ WtBr) {
  int z = blockIdx.z, bx = blockIdx.x, t = threadIdx.x;
  if (z < 2) {
    if (bx >= 128) return;
    tr_tile(z ? Wppro : Wppep, z ? WppTr : WppTp, 1024, 128, bx % 4, bx / 4, t);
  } else if (z < 6) {
    if (bx >= 400) return;
    const float* src = (z == 2) ? Wg1p : (z == 3) ? Wg2p : (z == 4) ? Wg1r : Wg2r;
    __bf16* dst = (z == 2) ? Wg1Tp : (z == 3) ? Wg2Tp : (z == 4) ? Wg1Tr : Wg2Tr;
    tr_tile(src, dst, 640, 640, bx % 20, bx / 20, t);
  } else {
    if (bx >= 560) return;
    const float* src = (z == 6) ? Wtp : Wtr;
    __bf16* dst = (z == 6) ? WtBp : WtBr;
    int i = bx * 256 + t;  // < 143360 float4s
    float4 v = ((const float4*)src)[i];
    bf16x4v o;
    o.x = (__bf16)v.x; o.y = (__bf16)v.y; o.z = (__bf16)v.z; o.w = (__bf16)v.w;
    ((bf16x4v*)dst)[i] = o;
  }
}

// ---------------------------------------------------------------------------
// Utility
// ---------------------------------------------------------------------------
__global__ __launch_bounds__(256) void zero_f32(float* __restrict__ p, int n) {
  int i = blockIdx.x * 256 + threadIdx.x;
  if (i < n) p[i] = 0.f;
}

__global__ __launch_bounds__(256) void rsqrt_k(const float* __restrict__ deg,
                                               float* __restrict__ dinv, int n) {
  int i = blockIdx.x * 256 + threadIdx.x;
  if (i < n) dinv[i] = rsqrtf(deg[i]);
}

// ---------------------------------------------------------------------------
// prep_pack merged: grid (4, 32, 17). z<16: pro (b=z, rw=y, c=x*256+t);
// z==16: pep (b=y<16, rw=x, c=t<128).
// ---------------------------------------------------------------------------
__global__ __launch_bounds__(256) void prep_pack_merged(
    const float* __restrict__ adjP, const float* __restrict__ adjR,
    uint32* __restrict__ packedP, uint32* __restrict__ packedR,
    float* __restrict__ degP, float* __restrict__ degR) {
  int t = threadIdx.x;
  const float* adj; uint32* packed; float* deg;
  int b, rw, c, L;
  if (blockIdx.z < 16) {
    L = LR; b = blockIdx.z; rw = blockIdx.y; c = blockIdx.x * 256 + t;
    adj = adjR; packed = packedR; deg = degR;
  } else {
    L = LP; b = blockIdx.y; rw = blockIdx.x; c = t;
    if (b >= 16 || c >= LP) return;
    adj = adjP; packed = packedP; deg = degP;
  }
  const float* adjB = adj + (size_t)b * L * L;
  uint32 w = 0;
  int rbase = rw * 32;
  #pragma unroll 8
  for (int j = 0; j < 32; ++j) {
    float a = adjB[(size_t)(rbase + j) * L + c];
    if (a != 0.f || (rbase + j) == c) w |= (1u << j);
  }
  packed[((size_t)b * (L >> 5) + rw) * L + c] = w;
  atomicAdd(deg + b * L + c, (float)__popc(w));
}

// ---------------------------------------------------------------------------
// pre_gemm merged (split-K pretrain partials): grid (144, SPLITK).
// bx<16: pep m-block bx; else pro m-block bx-16. by = k-slice.
// ---------------------------------------------------------------------------
__global__ __launch_bounds__(256) void pre_gemm(
    const float* __restrict__ XpP, const float* __restrict__ XpR,
    const __bf16* __restrict__ WppTp, const __bf16* __restrict__ WppTr,
    float* __restrict__ partP, float* __restrict__ partR) {
  int bx = blockIdx.x, s = blockIdx.y;
  int pep = bx < (BSZ * LP / 128);
  int m0 = (pep ? bx : bx - BSZ * LP / 128) * 128;
  const float* A = pep ? XpP : XpR;
  const ushort* B = (const ushort*)(pep ? WppTp : WppTr);
  int BL = pep ? BSZ * LP : BSZ * LR;
  float* part = (pep ? partP : partR) + (size_t)s * BL * DD;

  f32x4 acc[4][4];
  #pragma unroll
  for (int i = 0; i < 4; ++i)
    #pragma unroll
    for (int j = 0; j < 4; ++j) acc[i][j] = (f32x4){0.f, 0.f, 0.f, 0.f};
  mfma_core<1>(A, 1024, B, 1024, m0, 0, s * (1024 / SPLITK),
               (s + 1) * (1024 / SPLITK), acc);

  int t = threadIdx.x;
  int wave = t >> 6, lane = t & 63;
  int quad = lane >> 4, l16 = lane & 15;
  int wm = (wave >> 1) * 64, wn = (wave & 1) * 64;
  #pragma unroll
  for (int fi = 0; fi < 4; ++fi)
    #pragma unroll
    for (int r = 0; r < 4; ++r) {
      int m = m0 + wm + fi * 16 + quad * 4 + r;
      #pragma unroll
      for (int fj = 0; fj < 4; ++fj) {
        int n = wn + fj * 16 + l16;
        part[(size_t)m * DD + n] = acc[fi][fj][r];
      }
    }
}

// ---------------------------------------------------------------------------
// Encoder merged: embeddings + dense matmul + pretrain-partial reduce.
// grid (BLp + BLr, 128 threads)
// ---------------------------------------------------------------------------
__global__ __launch_bounds__(128) void encoder_merged(
    const int* __restrict__ xsP, const int* __restrict__ xssP,
    const int* __restrict__ x2P, const float* __restrict__ xdP,
    const float* __restrict__ WdP, const float* __restrict__ bdP,
    const float* __restrict__ maskP, const float* __restrict__ partP,
    const float* __restrict__ bppP, __bf16* __restrict__ encP,
    const int* __restrict__ xsR, const int* __restrict__ xssR,
    const int* __restrict__ x2R, const float* __restrict__ xdR,
    const float* __restrict__ WdR, const float* __restrict__ bdR,
    const float* __restrict__ maskR, const float* __restrict__ partR,
    const float* __restrict__ bppR, __bf16* __restrict__ encR,
    const float* __restrict__ Eseq, const float* __restrict__ Ess,
    const float* __restrict__ Etwo) {
  int gw = blockIdx.x;
  int t = threadIdx.x;
  int pep = gw < BSZ * LP;
  int row = pep ? gw : gw - BSZ * LP;
  int BL = pep ? BSZ * LP : BSZ * LR;
  int Kd = pep ? 3 : 23;
  const int* xs = pep ? xsP : xsR;
  const int* xss = pep ? xssP : xssR;
  const int* x2 = pep ? x2P : x2R;
  const float* xd = pep ? xdP : xdR;
  const float* Wd = pep ? WdP : WdR;
  const float* bd = pep ? bdP : bdR;
  const float* mask = pep ? maskP : maskR;
  const float* part = pep ? partP : partR;
  const float* bpp = pep ? bppP : bppR;
  __bf16* enc = pep ? encP : encR;

  float m = mask[row];
  int i0 = xs[row], i1 = xss[row], i2 = x2[row];
  __bf16* e = enc + (size_t)row * DG;
  e[t]        = (__bf16)(Eseq[i0 * DD + t] * m);
  e[DD + t]   = (__bf16)(Ess[i1 * DD + t] * m);
  e[2*DD + t] = (__bf16)(Etwo[i2 * DD + t] * m);
  float acc = bd[t];
  const float* xr = xd + (size_t)row * Kd;
  for (int i = 0; i < Kd; ++i) acc = fmaf(xr[i], Wd[i * DD + t], acc);
  e[3*DD + t] = (__bf16)(acc * m);
  // pretrain reduce -> cols 512..639
  float p = bpp[t];
  #pragma unroll
  for (int s = 0; s < SPLITK; ++s)
    p += part[(size_t)s * BL * DD + (size_t)row * DD + t];
  e[4*DD + t] = (__bf16)(p * m);
}

// ---------------------------------------------------------------------------
// linT merged: bufAT[d][row] = dinv[row] * sum_k src[row][k] * Wg[k][d]
// grid (144, 5): bx<16 pep n-block, else pro. by = m-block (d).
// (sharing dim y has grid-x stride 144 ≡ 0 mod 8 -> same-XCD L2 reuse)
// ---------------------------------------------------------------------------
__global__ __launch_bounds__(256) void linT_merged(
    const __bf16* __restrict__ WgTp, const __bf16* __restrict__ srcP,
    const float* __restrict__ dinvP, __bf16* __restrict__ dstP,
    const __bf16* __restrict__ WgTr, const __bf16* __restrict__ srcR,
    const float* __restrict__ dinvR, __bf16* __restrict__ dstR) {
  int bx = blockIdx.x;
  int pep = bx < (BSZ * LP / 128);
  int n0 = (pep ? bx : bx - BSZ * LP / 128) * 128;
  int m0 = blockIdx.y * 128;
  int BL = pep ? BSZ * LP : BSZ * LR;
  const __bf16* A = pep ? WgTp : WgTr;
  const ushort* B = (const ushort*)(pep ? srcP : srcR);
  const float* dinv = pep ? dinvP : dinvR;
  __bf16* dst = pep ? dstP : dstR;

  f32x4 acc[4][4];
  #pragma unroll
  for (int i = 0; i < 4; ++i)
    #pragma unroll
    for (int j = 0; j < 4; ++j) acc[i][j] = (f32x4){0.f, 0.f, 0.f, 0.f};
  mfma_core<0>(A, DG, B, DG, m0, n0, 0, DG, acc);

  int t = threadIdx.x;
  int wave = t >> 6, lane = t & 63;
  int quad = lane >> 4, l16 = lane & 15;
  int wm = (wave >> 1) * 64, wn = (wave & 1) * 64;
  #pragma unroll
  for (int fi = 0; fi < 4; ++fi)
    #pragma unroll
    for (int r = 0; r < 4; ++r) {
      int m = m0 + wm + fi * 16 + quad * 4 + r;
      #pragma unroll
      for (int fj = 0; fj < 4; ++fj) {
        int n = n0 + wn + fj * 16 + l16;
        dst[(size_t)m * BL + n] = (__bf16)(acc[fi][fj][r] * dinv[n]);
      }
    }
}

// ---------------------------------------------------------------------------
// agg merged, XCD-aware grid: (80, 9).
// bx encodes (b = bx/5, n0 = (bx%5)*128). by==0: pep (m0=0); else pro
// m-block by-1. Same-(b,n0) blocks differ by 80 in linear id (80%8==0) ->
// same XCD -> Xt slice served from local L2 instead of HBM refetch.
// Y[b,c,d] = relu(dinv*acc + bias[d] (+encE)) * (mask?)
// ---------------------------------------------------------------------------
__global__ __launch_bounds__(256) void agg_merged(
    const uint32* __restrict__ packedP, const __bf16* __restrict__ XtP,
    const float* __restrict__ dinvP, const float* __restrict__ biasP,
    const __bf16* __restrict__ encEP, const float* __restrict__ maskP,
    __bf16* __restrict__ YP,
    const uint32* __restrict__ packedR, const __bf16* __restrict__ XtR,
    const float* __restrict__ dinvR, const float* __restrict__ biasR,
    const __bf16* __restrict__ encER, const float* __restrict__ maskR,
    __bf16* __restrict__ YR) {
  int bx = blockIdx.x;
  int b = bx / 5;
  int n0 = (bx % 5) * 128;
  int pep = (blockIdx.y == 0);
  int L = pep ? LP : LR;
  int BL = BSZ * L;
  int m0 = pep ? 0 : (blockIdx.y - 1) * 128;
  const uint32* pb = (pep ? packedP : packedR) + (size_t)b * (L >> 5) * L;
  const ushort* Bb = (const ushort*)(pep ? XtP : XtR) + (size_t)b * L;
  const float* dinv = pep ? dinvP : dinvR;
  const float* bias = pep ? biasP : biasR;
  const __bf16* encE = pep ? encEP : encER;
  const float* mask = pep ? maskP : maskR;
  __bf16* Y = pep ? YP : YR;

  f32x4 acc[4][4];
  #pragma unroll
  for (int i = 0; i < 4; ++i)
    #pragma unroll
    for (int j = 0; j < 4; ++j) acc[i][j] = (f32x4){0.f, 0.f, 0.f, 0.f};
  agg_core(pb, L, Bb, BL, m0, n0, acc);

  int t = threadIdx.x;
  int wave = t >> 6, lane = t & 63;
  int quad = lane >> 4, l16 = lane & 15;
  int wm = (wave >> 1) * 64, wn = (wave & 1) * 64;
  int gRow = b * L;
  #pragma unroll
  for (int fi = 0; fi < 4; ++fi)
    #pragma unroll
    for (int r = 0; r < 4; ++r) {
      int m = m0 + wm + fi * 16 + quad * 4 + r;
      int gi = gRow + m;
      float di = dinv[gi];
      float rm = mask ? mask[gi] : 1.f;
      #pragma unroll
      for (int fj = 0; fj < 4; ++fj) {
        int n = n0 + wn + fj * 16 + l16;
        float v = acc[fi][fj][r] * di + bias[n];
        if (encE) v += (float)encE[(size_t)gi * DG + n];
        v = fmaxf(v, 0.f);
        v *= rm;
        Y[(size_t)gi * DG + n] = (__bf16)v;
      }
    }
}

// ---------------------------------------------------------------------------
// fct merged: grid (8, 7, 18). bz<16: pro (b=bz, n over L); bz>=16: pep
// (n over BL flattened, b=n>>7). out f32. (kh-sharing blocks already have
// linear-id stride 8 -> same XCD.)
// ---------------------------------------------------------------------------
__global__ __launch_bounds__(256) void fct_merged(
    const __bf16* __restrict__ WtBp, const float* __restrict__ btp,
    const __bf16* __restrict__ Yp, float* __restrict__ outP,
    const __bf16* __restrict__ WtBr, const float* __restrict__ btr,
    const __bf16* __restrict__ Yr, float* __restrict__ outR) {
  int kh = blockIdx.y;
  int pro = (blockIdx.z < 16);
  const __bf16* A;
  const ushort* B;
  const float* bt;
  int n0;
  if (pro) {
    A = WtBr + (size_t)kh * DD * DG;
    B = (const ushort*)(Yr + (size_t)blockIdx.z * LR * DG);
    bt = btr;
    n0 = blockIdx.x * 128;
  } else {
    A = WtBp + (size_t)kh * DD * DG;
    B = (const ushort*)Yp;
    bt = btp;
    n0 = ((blockIdx.z - 16) * 8 + blockIdx.x) * 128;
  }

  f32x4 acc[4][4];
  #pragma unroll
  for (int i = 0; i < 4; ++i)
    #pragma unroll
    for (int j = 0; j < 4; ++j) acc[i][j] = (f32x4){0.f, 0.f, 0.f, 0.f};
  mfma_core<0>(A, DG, B, DG, 0, n0, 0, DG, acc);

  int t = threadIdx.x;
  int wave = t >> 6, lane = t & 63;
  int quad = lane >> 4, l16 = lane & 15;
  int wm = (wave >> 1) * 64, wn = (wave & 1) * 64;
  #pragma unroll
  for (int fi = 0; fi < 4; ++fi)
    #pragma unroll
    for (int r = 0; r < 4; ++r) {
      int m = wm + fi * 16 + quad * 4 + r;
      float bb = bt[kh * DD + m];
      #pragma unroll
      for (int fj = 0; fj < 4; ++fj) {
        int n = n0 + wn + fj * 16 + l16;
        float v = fmaxf(acc[fi][fj][r] + bb, 0.f);
        if (pro) {
          outR[((size_t)(kh * BSZ + blockIdx.z) * DD + m) * LR + n] = v;
        } else {
          int b = n >> 7, l = n & 127;
          outP[((size_t)(kh * BSZ + b) * DD + m) * LP + l] = v;
        }
      }
    }
}

// ---------------------------------------------------------------------------
extern "C" void kernel_launch(void* const* d_in, const int* in_sizes, int n_in,
                              void* d_out, int out_size, void* d_ws, size_t ws_size,
                              hipStream_t stream) {
  const int*   x_pep          = (const int*)d_in[0];
  const int*   x_ss_pep       = (const int*)d_in[1];
  const int*   x_2_pep        = (const int*)d_in[2];
  const float* x_dense_pep    = (const float*)d_in[3];
  const float* x_pretrain_pep = (const float*)d_in[4];
  const int*   x_pro          = (const int*)d_in[5];
  const int*   x_ss_pro       = (const int*)d_in[6];
  const int*   x_2_pro        = (const int*)d_in[7];
  const float* x_dense_pro    = (const float*)d_in[8];
  const float* x_pretrain_pro = (const float*)d_in[9];
  const float* x_edge_pep     = (const float*)d_in[10];
  const float* x_edge_pro     = (const float*)d_in[11];
  const float* mask_pep       = (const float*)d_in[12];
  const float* mask_pro       = (const float*)d_in[13];
  const float* E_seq          = (const float*)d_in[14];
  const float* E_ss           = (const float*)d_in[15];
  const float* E_two          = (const float*)d_in[16];
  const float* W_dpep         = (const float*)d_in[17];
  const float* b_dpep         = (const float*)d_in[18];
  const float* W_dpro         = (const float*)d_in[19];
  const float* b_dpro         = (const float*)d_in[20];
  const float* W_ppep         = (const float*)d_in[21];
  const float* b_ppep         = (const float*)d_in[22];
  const float* W_ppro         = (const float*)d_in[23];
  const float* b_ppro         = (const float*)d_in[24];
  const float* Wg_pep1        = (const float*)d_in[25];
  const float* bg_pep1        = (const float*)d_in[26];
  const float* Wg_pep2        = (const float*)d_in[27];
  const float* bg_pep2        = (const float*)d_in[28];
  const float* Wg_pro1        = (const float*)d_in[29];
  const float* bg_pro1        = (const float*)d_in[30];
  const float* Wg_pro2        = (const float*)d_in[31];
  const float* bg_pro2        = (const float*)d_in[32];
  const float* Wt_pep         = (const float*)d_in[33];
  const float* bt_pep         = (const float*)d_in[34];
  const float* Wt_pro         = (const float*)d_in[35];
  const float* bt_pro         = (const float*)d_in[36];

  float* out = (float*)d_out;
  const int BLp = BSZ * LP;   // 2048
  const int BLr = BSZ * LR;   // 16384
  const size_t out_pro_off = (size_t)KH * BSZ * DD * LP;

  // Workspace layout (~117 MB)
  char* w = (char*)d_ws;
  __bf16* encBp  = (__bf16*)w; w += (size_t)BLp * DG * 2;
  __bf16* encBr  = (__bf16*)w; w += (size_t)BLr * DG * 2;
  __bf16* bufATp = (__bf16*)w; w += (size_t)DG * BLp * 2;
  __bf16* bufATr = (__bf16*)w; w += (size_t)DG * BLr * 2;
  __bf16* bufYp  = (__bf16*)w; w += (size_t)BLp * DG * 2;
  __bf16* bufYr  = (__bf16*)w; w += (size_t)BLr * DG * 2;
  __bf16* WppTp  = (__bf16*)w; w += (size_t)DD * 1024 * 2;
  __bf16* WppTr  = (__bf16*)w; w += (size_t)DD * 1024 * 2;
  __bf16* Wg1Tp  = (__bf16*)w; w += (size_t)DG * DG * 2;
  __bf16* Wg2Tp  = (__bf16*)w; w += (size_t)DG * DG * 2;
  __bf16* Wg1Tr  = (__bf16*)w; w += (size_t)DG * DG * 2;
  __bf16* Wg2Tr  = (__bf16*)w; w += (size_t)DG * DG * 2;
  __bf16* WtBp   = (__bf16*)w; w += (size_t)KH * DD * DG * 2;
  __bf16* WtBr   = (__bf16*)w; w += (size_t)KH * DD * DG * 2;
  uint32* packedP = (uint32*)w; w += (size_t)BSZ * (LP / 32) * LP * 4;
  uint32* packedR = (uint32*)w; w += (size_t)BSZ * (LR / 32) * LR * 4;
  float* degP  = (float*)w; w += (size_t)BLp * 4;
  float* degR  = (float*)w; w += (size_t)BLr * 4;
  float* dinvP = (float*)w; w += (size_t)BLp * 4;
  float* dinvR = (float*)w; w += (size_t)BLr * 4;
  float* partP = (float*)w; w += (size_t)SPLITK * BLp * DD * 4;
  float* partR = (float*)w; w += (size_t)SPLITK * BLr * DD * 4;

  // 1. weights
  prep_weights<<<dim3(560, 1, 8), 256, 0, stream>>>(
      W_ppep, W_ppro, Wg_pep1, Wg_pep2, Wg_pro1, Wg_pro2, Wt_pep, Wt_pro,
      WppTp, WppTr, Wg1Tp, Wg2Tp, Wg1Tr, Wg2Tr, WtBp, WtBr);
  // 2-4. adjacency prep
  zero_f32<<<(BLp + BLr) / 256, 256, 0, stream>>>(degP, BLp + BLr);
  prep_pack_merged<<<dim3(4, 32, 17), 256, 0, stream>>>(
      x_edge_pep, x_edge_pro, packedP, packedR, degP, degR);
  rsqrt_k<<<(BLp + BLr) / 256, 256, 0, stream>>>(degP, dinvP, BLp + BLr);
  // 5. pretrain split-K partials
  pre_gemm<<<dim3((BLp + BLr) / 128, SPLITK), 256, 0, stream>>>(
      x_pretrain_pep, x_pretrain_pro, WppTp, WppTr, partP, partR);
  // 6. encoder (+ pretrain reduce)
  encoder_merged<<<BLp + BLr, 128, 0, stream>>>(
      x_pep, x_ss_pep, x_2_pep, x_dense_pep, W_dpep, b_dpep, mask_pep, partP,
      b_ppep, encBp,
      x_pro, x_ss_pro, x_2_pro, x_dense_pro, W_dpro, b_dpro, mask_pro, partR,
      b_ppro, encBr,
      E_seq, E_ss, E_two);
  // 7-10. GCN
  linT_merged<<<dim3((BLp + BLr) / 128, DG / 128), 256, 0, stream>>>(
      Wg1Tp, encBp, dinvP, bufATp, Wg1Tr, encBr, dinvR, bufATr);
  agg_merged<<<dim3(80, 9), 256, 0, stream>>>(
      packedP, bufATp, dinvP, bg_pep1, nullptr, nullptr, bufYp,
      packedR, bufATr, dinvR, bg_pro1, nullptr, nullptr, bufYr);
  linT_merged<<<dim3((BLp + BLr) / 128, DG / 128), 256, 0, stream>>>(
      Wg2Tp, bufYp, dinvP, bufATp, Wg2Tr, bufYr, dinvR, bufATr);
  agg_merged<<<dim3(80, 9), 256, 0, stream>>>(
      packedP, bufATp, dinvP, bg_pep2, encBp, mask_pep, bufYp,
      packedR, bufATr, dinvR, bg_pro2, encBr, mask_pro, bufYr);
  // 11. fct
  fct_merged<<<dim3(LR / 128, KH, 18), 256, 0, stream>>>(
      WtBp, bt_pep, bufYp, out,
      WtBr, bt_pro, bufYr, out + out_pro_off);
}

// Round 7
// 469.422 us; speedup vs baseline: 4.8480x; 1.0721x over previous
//
#include <hip/hip_runtime.h>
#include <hip/hip_bf16.h>

// Problem constants
#define BSZ 16
#define LP 128
#define LR 1024
#define DD 128
#define DG 640
#define KH 7
#define SPLITK 4

typedef __bf16 bf16x8 __attribute__((ext_vector_type(8)));
typedef __bf16 bf16x4v __attribute__((ext_vector_type(4)));
typedef float f32x4 __attribute__((ext_vector_type(4)));
typedef unsigned int uint32;

// ---------------------------------------------------------------------------
// MFMA core: 128x128 tile, BK=64, 4 waves, software-pipelined K-loop:
// loads for iter k+1 are issued BEFORE compute(k), so their latency is
// hidden under the MFMA phase instead of being exposed between barriers.
// AF32=1: A is f32, converted to bf16 during staging.
// ---------------------------------------------------------------------------
template <int AF32>
__device__ __forceinline__ void mfma_core(
    const void* __restrict__ A_, int lda,
    const ushort* __restrict__ Bb, int ldb,
    int m0, int n0, int kStart, int kEnd, f32x4 (&acc)[4][4]) {
  __shared__ __align__(16) ushort As[128 * 72];
  __shared__ __align__(16) ushort Bs[128 * 72];
  int t = threadIdx.x;
  int wave = t >> 6, lane = t & 63;
  int quad = lane >> 4, l16 = lane & 15;
  int wm = (wave >> 1) * 64, wn = (wave & 1) * 64;
  int r1 = t >> 2, o1 = (t & 3) * 16;

  int4 b00, b01, b10, b11;
  int4 a00, a01, a10, a11;
  float4 af32[8];

  auto load_k = [&](int k0) {
    b00 = *(const int4*)(Bb + (size_t)(n0 + r1) * ldb + k0 + o1);
    b01 = *(const int4*)(Bb + (size_t)(n0 + r1) * ldb + k0 + o1 + 8);
    b10 = *(const int4*)(Bb + (size_t)(n0 + r1 + 64) * ldb + k0 + o1);
    b11 = *(const int4*)(Bb + (size_t)(n0 + r1 + 64) * ldb + k0 + o1 + 8);
    if (AF32) {
      const float* Af = (const float*)A_;
      #pragma unroll
      for (int s = 0; s < 8; ++s) {
        int idx = t + s * 256;
        int row = idx >> 4, c4 = (idx & 15) * 4;
        af32[s] = *(const float4*)(Af + (size_t)(m0 + row) * lda + k0 + c4);
      }
    } else {
      const ushort* Ab = (const ushort*)A_;
      a00 = *(const int4*)(Ab + (size_t)(m0 + r1) * lda + k0 + o1);
      a01 = *(const int4*)(Ab + (size_t)(m0 + r1) * lda + k0 + o1 + 8);
      a10 = *(const int4*)(Ab + (size_t)(m0 + r1 + 64) * lda + k0 + o1);
      a11 = *(const int4*)(Ab + (size_t)(m0 + r1 + 64) * lda + k0 + o1 + 8);
    }
  };

  load_k(kStart);
  for (int k0 = kStart; k0 < kEnd; k0 += 64) {
    __syncthreads();   // previous iteration's LDS fully consumed
    if (AF32) {
      #pragma unroll
      for (int s = 0; s < 8; ++s) {
        int idx = t + s * 256;
        int row = idx >> 4, c4 = (idx & 15) * 4;
        ushort4 u; __bf16 h;
        h = (__bf16)af32[s].x; u.x = *(ushort*)&h;
        h = (__bf16)af32[s].y; u.y = *(ushort*)&h;
        h = (__bf16)af32[s].z; u.z = *(ushort*)&h;
        h = (__bf16)af32[s].w; u.w = *(ushort*)&h;
        *(ushort4*)&As[row * 72 + c4] = u;
      }
    } else {
      *(int4*)&As[r1 * 72 + o1] = a00;
      *(int4*)&As[r1 * 72 + o1 + 8] = a01;
      *(int4*)&As[(r1 + 64) * 72 + o1] = a10;
      *(int4*)&As[(r1 + 64) * 72 + o1 + 8] = a11;
    }
    *(int4*)&Bs[r1 * 72 + o1] = b00;
    *(int4*)&Bs[r1 * 72 + o1 + 8] = b01;
    *(int4*)&Bs[(r1 + 64) * 72 + o1] = b10;
    *(int4*)&Bs[(r1 + 64) * 72 + o1 + 8] = b11;
    __syncthreads();
    if (k0 + 64 < kEnd) load_k(k0 + 64);  // prefetch under compute
    #pragma unroll
    for (int kc = 0; kc < 2; ++kc) {
      bf16x8 af[4], bfr[4];
      #pragma unroll
      for (int fi = 0; fi < 4; ++fi)
        af[fi] = *(const bf16x8*)&As[(wm + fi * 16 + l16) * 72 + kc * 32 + quad * 8];
      #pragma unroll
      for (int fj = 0; fj < 4; ++fj)
        bfr[fj] = *(const bf16x8*)&Bs[(wn + fj * 16 + l16) * 72 + kc * 32 + quad * 8];
      #pragma unroll
      for (int fi = 0; fi < 4; ++fi)
        #pragma unroll
        for (int fj = 0; fj < 4; ++fj)
          acc[fi][fj] = __builtin_amdgcn_mfma_f32_16x16x32_bf16(
              af[fi], bfr[fj], acc[fi][fj], 0, 0, 0);
    }
  }
}

// ---------------------------------------------------------------------------
// agg core: A built in-register from packed adjacency bits, BK=64,
// same software-pipelined structure.
// acc[c][d] += sum_r Ahat[r,c] * Xt[d][bcol + r]
// ---------------------------------------------------------------------------
__device__ __forceinline__ void agg_core(
    const uint32* __restrict__ pb, int L,
    const ushort* __restrict__ Bb, int ldb,
    int m0, int n0, f32x4 (&acc)[4][4]) {
  __shared__ __align__(16) ushort Bs[128 * 72];
  __shared__ uint32 Aw[2][128];
  int t = threadIdx.x;
  int wave = t >> 6, lane = t & 63;
  int quad = lane >> 4, l16 = lane & 15;
  int wm = (wave >> 1) * 64, wn = (wave & 1) * 64;
  int r1 = t >> 2, o1 = (t & 3) * 16;
  int half = t >> 7, cc = t & 127;

  int4 b00, b01, b10, b11;
  uint32 w;
  auto load_k = [&](int k0) {
    b00 = *(const int4*)(Bb + (size_t)(n0 + r1) * ldb + k0 + o1);
    b01 = *(const int4*)(Bb + (size_t)(n0 + r1) * ldb + k0 + o1 + 8);
    b10 = *(const int4*)(Bb + (size_t)(n0 + r1 + 64) * ldb + k0 + o1);
    b11 = *(const int4*)(Bb + (size_t)(n0 + r1 + 64) * ldb + k0 + o1 + 8);
    w = pb[(size_t)((k0 >> 5) + half) * L + m0 + cc];
  };

  load_k(0);
  for (int k0 = 0; k0 < L; k0 += 64) {
    __syncthreads();
    *(int4*)&Bs[r1 * 72 + o1] = b00;
    *(int4*)&Bs[r1 * 72 + o1 + 8] = b01;
    *(int4*)&Bs[(r1 + 64) * 72 + o1] = b10;
    *(int4*)&Bs[(r1 + 64) * 72 + o1 + 8] = b11;
    Aw[half][cc] = w;
    __syncthreads();
    if (k0 + 64 < L) load_k(k0 + 64);  // prefetch under compute
    #pragma unroll
    for (int kc = 0; kc < 2; ++kc) {
      bf16x8 af[4], bfr[4];
      #pragma unroll
      for (int fj = 0; fj < 4; ++fj)
        bfr[fj] = *(const bf16x8*)&Bs[(wn + fj * 16 + l16) * 72 + kc * 32 + quad * 8];
      #pragma unroll
      for (int fi = 0; fi < 4; ++fi) {
        uint32 bits = (Aw[kc][wm + fi * 16 + l16] >> (quad * 8)) & 0xffu;
        int4 p;
        p.x = (int)((((bits >> 0) & 1) ? 0x3F80u : 0u) | (((bits >> 1) & 1) ? 0x3F800000u : 0u));
        p.y = (int)((((bits >> 2) & 1) ? 0x3F80u : 0u) | (((bits >> 3) & 1) ? 0x3F800000u : 0u));
        p.z = (int)((((bits >> 4) & 1) ? 0x3F80u : 0u) | (((bits >> 5) & 1) ? 0x3F800000u : 0u));
        p.w = (int)((((bits >> 6) & 1) ? 0x3F80u : 0u) | (((bits >> 7) & 1) ? 0x3F800000u : 0u));
        af[fi] = *(bf16x8*)&p;
      }
      #pragma unroll
      for (int fi = 0; fi < 4; ++fi)
        #pragma unroll
        for (int fj = 0; fj < 4; ++fj)
          acc[fi][fj] = __builtin_amdgcn_mfma_f32_16x16x32_bf16(
              af[fi], bfr[fj], acc[fi][fj], 0, 0, 0);
    }
  }
}

// ---------------------------------------------------------------------------
// prep_weights: all weight conversions/transposes in one dispatch.
// grid (560, 1, 8)
// ---------------------------------------------------------------------------
__device__ __forceinline__ void tr_tile(const float* __restrict__ src,
                                        __bf16* __restrict__ dst,
                                        int R, int C, int cb, int rb, int t) {
  __shared__ float T[32][33];
  int r0 = rb * 32, c0 = cb * 32;
  #pragma unroll
  for (int s = 0; s < 4; ++s) {
    int idx = t + s * 256;
    int r = idx >> 5, c = idx & 31;
    T[r][c] = src[(size_t)(r0 + r) * C + c0 + c];
  }
  __syncthreads();
  #pragma unroll
  for (int s = 0; s < 4; ++s) {
    int idx = t + s * 256;
    int c = idx >> 5, r = idx & 31;
    dst[(size_t)(c0 + c) * R + r0 + r] = (__bf16)T[r][c];
  }
}

__global__ __launch_bounds__(256) void prep_weights(
    const float* __restrict__ Wppep, const float* __restrict__ Wppro,
    const float* __restrict__ Wg1p, const float* __restrict__ Wg2p,
    const float* __restrict__ Wg1r, const float* __restrict__ Wg2r,
    const float* __restrict__ Wtp, const float* __restrict__ Wtr,
    __bf16* __restrict__ WppTp, __bf16* __restrict__ WppTr,
    __bf16* __restrict__ Wg1Tp, __bf16* __restrict__ Wg2Tp,
    __bf16* __restrict__ Wg1Tr, __bf16* __restrict__ Wg2Tr,
    __bf16* __restrict__ WtBp, __bf16* __restrict__ WtBr) {
  int z = blockIdx.z, bx = blockIdx.x, t = threadIdx.x;
  if (z < 2) {
    if (bx >= 128) return;
    tr_tile(z ? Wppro : Wppep, z ? WppTr : WppTp, 1024, 128, bx % 4, bx / 4, t);
  } else if (z < 6) {
    if (bx >= 400) return;
    const float* src = (z == 2) ? Wg1p : (z == 3) ? Wg2p : (z == 4) ? Wg1r : Wg2r;
    __bf16* dst = (z == 2) ? Wg1Tp : (z == 3) ? Wg2Tp : (z == 4) ? Wg1Tr : Wg2Tr;
    tr_tile(src, dst, 640, 640, bx % 20, bx / 20, t);
  } else {
    if (bx >= 560) return;
    const float* src = (z == 6) ? Wtp : Wtr;
    __bf16* dst = (z == 6) ? WtBp : WtBr;
    int i = bx * 256 + t;  // < 143360 float4s
    float4 v = ((const float4*)src)[i];
    bf16x4v o;
    o.x = (__bf16)v.x; o.y = (__bf16)v.y; o.z = (__bf16)v.z; o.w = (__bf16)v.w;
    ((bf16x4v*)dst)[i] = o;
  }
}

// ---------------------------------------------------------------------------
// Utility
// ---------------------------------------------------------------------------
__global__ __launch_bounds__(256) void zero_f32(float* __restrict__ p, int n) {
  int i = blockIdx.x * 256 + threadIdx.x;
  if (i < n) p[i] = 0.f;
}

__global__ __launch_bounds__(256) void rsqrt_k(const float* __restrict__ deg,
                                               float* __restrict__ dinv, int n) {
  int i = blockIdx.x * 256 + threadIdx.x;
  if (i < n) dinv[i] = rsqrtf(deg[i]);
}

// ---------------------------------------------------------------------------
// prep_pack merged: grid (4, 32, 17). z<16: pro (b=z, rw=y, c=x*256+t);
// z==16: pep (b=y<16, rw=x, c=t<128).
// ---------------------------------------------------------------------------
__global__ __launch_bounds__(256) void prep_pack_merged(
    const float* __restrict__ adjP, const float* __restrict__ adjR,
    uint32* __restrict__ packedP, uint32* __restrict__ packedR,
    float* __restrict__ degP, float* __restrict__ degR) {
  int t = threadIdx.x;
  const float* adj; uint32* packed; float* deg;
  int b, rw, c, L;
  if (blockIdx.z < 16) {
    L = LR; b = blockIdx.z; rw = blockIdx.y; c = blockIdx.x * 256 + t;
    adj = adjR; packed = packedR; deg = degR;
  } else {
    L = LP; b = blockIdx.y; rw = blockIdx.x; c = t;
    if (b >= 16 || c >= LP) return;
    adj = adjP; packed = packedP; deg = degP;
  }
  const float* adjB = adj + (size_t)b * L * L;
  uint32 w = 0;
  int rbase = rw * 32;
  #pragma unroll 8
  for (int j = 0; j < 32; ++j) {
    float a = adjB[(size_t)(rbase + j) * L + c];
    if (a != 0.f || (rbase + j) == c) w |= (1u << j);
  }
  packed[((size_t)b * (L >> 5) + rw) * L + c] = w;
  atomicAdd(deg + b * L + c, (float)__popc(w));
}

// ---------------------------------------------------------------------------
// pre_gemm merged (split-K pretrain partials): grid (144, SPLITK).
// bx<16: pep m-block bx; else pro m-block bx-16. by = k-slice.
// ---------------------------------------------------------------------------
__global__ __launch_bounds__(256) void pre_gemm(
    const float* __restrict__ XpP, const float* __restrict__ XpR,
    const __bf16* __restrict__ WppTp, const __bf16* __restrict__ WppTr,
    float* __restrict__ partP, float* __restrict__ partR) {
  int bx = blockIdx.x, s = blockIdx.y;
  int pep = bx < (BSZ * LP / 128);
  int m0 = (pep ? bx : bx - BSZ * LP / 128) * 128;
  const float* A = pep ? XpP : XpR;
  const ushort* B = (const ushort*)(pep ? WppTp : WppTr);
  int BL = pep ? BSZ * LP : BSZ * LR;
  float* part = (pep ? partP : partR) + (size_t)s * BL * DD;

  f32x4 acc[4][4];
  #pragma unroll
  for (int i = 0; i < 4; ++i)
    #pragma unroll
    for (int j = 0; j < 4; ++j) acc[i][j] = (f32x4){0.f, 0.f, 0.f, 0.f};
  mfma_core<1>(A, 1024, B, 1024, m0, 0, s * (1024 / SPLITK),
               (s + 1) * (1024 / SPLITK), acc);

  int t = threadIdx.x;
  int wave = t >> 6, lane = t & 63;
  int quad = lane >> 4, l16 = lane & 15;
  int wm = (wave >> 1) * 64, wn = (wave & 1) * 64;
  #pragma unroll
  for (int fi = 0; fi < 4; ++fi)
    #pragma unroll
    for (int r = 0; r < 4; ++r) {
      int m = m0 + wm + fi * 16 + quad * 4 + r;
      #pragma unroll
      for (int fj = 0; fj < 4; ++fj) {
        int n = wn + fj * 16 + l16;
        part[(size_t)m * DD + n] = acc[fi][fj][r];
      }
    }
}

// ---------------------------------------------------------------------------
// Encoder merged: embeddings + dense matmul + pretrain-partial reduce.
// grid (BLp + BLr, 128 threads)
// ---------------------------------------------------------------------------
__global__ __launch_bounds__(128) void encoder_merged(
    const int* __restrict__ xsP, const int* __restrict__ xssP,
    const int* __restrict__ x2P, const float* __restrict__ xdP,
    const float* __restrict__ WdP, const float* __restrict__ bdP,
    const float* __restrict__ maskP, const float* __restrict__ partP,
    const float* __restrict__ bppP, __bf16* __restrict__ encP,
    const int* __restrict__ xsR, const int* __restrict__ xssR,
    const int* __restrict__ x2R, const float* __restrict__ xdR,
    const float* __restrict__ WdR, const float* __restrict__ bdR,
    const float* __restrict__ maskR, const float* __restrict__ partR,
    const float* __restrict__ bppR, __bf16* __restrict__ encR,
    const float* __restrict__ Eseq, const float* __restrict__ Ess,
    const float* __restrict__ Etwo) {
  int gw = blockIdx.x;
  int t = threadIdx.x;
  int pep = gw < BSZ * LP;
  int row = pep ? gw : gw - BSZ * LP;
  int BL = pep ? BSZ * LP : BSZ * LR;
  int Kd = pep ? 3 : 23;
  const int* xs = pep ? xsP : xsR;
  const int* xss = pep ? xssP : xssR;
  const int* x2 = pep ? x2P : x2R;
  const float* xd = pep ? xdP : xdR;
  const float* Wd = pep ? WdP : WdR;
  const float* bd = pep ? bdP : bdR;
  const float* mask = pep ? maskP : maskR;
  const float* part = pep ? partP : partR;
  const float* bpp = pep ? bppP : bppR;
  __bf16* enc = pep ? encP : encR;

  float m = mask[row];
  int i0 = xs[row], i1 = xss[row], i2 = x2[row];
  __bf16* e = enc + (size_t)row * DG;
  e[t]        = (__bf16)(Eseq[i0 * DD + t] * m);
  e[DD + t]   = (__bf16)(Ess[i1 * DD + t] * m);
  e[2*DD + t] = (__bf16)(Etwo[i2 * DD + t] * m);
  float acc = bd[t];
  const float* xr = xd + (size_t)row * Kd;
  for (int i = 0; i < Kd; ++i) acc = fmaf(xr[i], Wd[i * DD + t], acc);
  e[3*DD + t] = (__bf16)(acc * m);
  // pretrain reduce -> cols 512..639
  float p = bpp[t];
  #pragma unroll
  for (int s = 0; s < SPLITK; ++s)
    p += part[(size_t)s * BL * DD + (size_t)row * DD + t];
  e[4*DD + t] = (__bf16)(p * m);
}

// ---------------------------------------------------------------------------
// linT merged: bufAT[d][row] = dinv[row] * sum_k src[row][k] * Wg[k][d]
// grid (144, 5): bx<16 pep n-block, else pro. by = m-block (d).
// ---------------------------------------------------------------------------
__global__ __launch_bounds__(256) void linT_merged(
    const __bf16* __restrict__ WgTp, const __bf16* __restrict__ srcP,
    const float* __restrict__ dinvP, __bf16* __restrict__ dstP,
    const __bf16* __restrict__ WgTr, const __bf16* __restrict__ srcR,
    const float* __restrict__ dinvR, __bf16* __restrict__ dstR) {
  int bx = blockIdx.x;
  int pep = bx < (BSZ * LP / 128);
  int n0 = (pep ? bx : bx - BSZ * LP / 128) * 128;
  int m0 = blockIdx.y * 128;
  int BL = pep ? BSZ * LP : BSZ * LR;
  const __bf16* A = pep ? WgTp : WgTr;
  const ushort* B = (const ushort*)(pep ? srcP : srcR);
  const float* dinv = pep ? dinvP : dinvR;
  __bf16* dst = pep ? dstP : dstR;

  f32x4 acc[4][4];
  #pragma unroll
  for (int i = 0; i < 4; ++i)
    #pragma unroll
    for (int j = 0; j < 4; ++j) acc[i][j] = (f32x4){0.f, 0.f, 0.f, 0.f};
  mfma_core<0>(A, DG, B, DG, m0, n0, 0, DG, acc);

  int t = threadIdx.x;
  int wave = t >> 6, lane = t & 63;
  int quad = lane >> 4, l16 = lane & 15;
  int wm = (wave >> 1) * 64, wn = (wave & 1) * 64;
  #pragma unroll
  for (int fi = 0; fi < 4; ++fi)
    #pragma unroll
    for (int r = 0; r < 4; ++r) {
      int m = m0 + wm + fi * 16 + quad * 4 + r;
      #pragma unroll
      for (int fj = 0; fj < 4; ++fj) {
        int n = n0 + wn + fj * 16 + l16;
        dst[(size_t)m * BL + n] = (__bf16)(acc[fi][fj][r] * dinv[n]);
      }
    }
}

// ---------------------------------------------------------------------------
// agg merged, XCD-aware grid: (80, 9).
// bx encodes (b = bx/5, n0 = (bx%5)*128). by==0: pep (m0=0); else pro
// m-block by-1. Same-(b,n0) blocks differ by 80 (80%8==0) -> same XCD.
// Y[b,c,d] = relu(dinv*acc + bias[d] (+encE)) * (mask?)
// ---------------------------------------------------------------------------
__global__ __launch_bounds__(256) void agg_merged(
    const uint32* __restrict__ packedP, const __bf16* __restrict__ XtP,
    const float* __restrict__ dinvP, const float* __restrict__ biasP,
    const __bf16* __restrict__ encEP, const float* __restrict__ maskP,
    __bf16* __restrict__ YP,
    const uint32* __restrict__ packedR, const __bf16* __restrict__ XtR,
    const float* __restrict__ dinvR, const float* __restrict__ biasR,
    const __bf16* __restrict__ encER, const float* __restrict__ maskR,
    __bf16* __restrict__ YR) {
  int bx = blockIdx.x;
  int b = bx / 5;
  int n0 = (bx % 5) * 128;
  int pep = (blockIdx.y == 0);
  int L = pep ? LP : LR;
  int BL = BSZ * L;
  int m0 = pep ? 0 : (blockIdx.y - 1) * 128;
  const uint32* pb = (pep ? packedP : packedR) + (size_t)b * (L >> 5) * L;
  const ushort* Bb = (const ushort*)(pep ? XtP : XtR) + (size_t)b * L;
  const float* dinv = pep ? dinvP : dinvR;
  const float* bias = pep ? biasP : biasR;
  const __bf16* encE = pep ? encEP : encER;
  const float* mask = pep ? maskP : maskR;
  __bf16* Y = pep ? YP : YR;

  f32x4 acc[4][4];
  #pragma unroll
  for (int i = 0; i < 4; ++i)
    #pragma unroll
    for (int j = 0; j < 4; ++j) acc[i][j] = (f32x4){0.f, 0.f, 0.f, 0.f};
  agg_core(pb, L, Bb, BL, m0, n0, acc);

  int t = threadIdx.x;
  int wave = t >> 6, lane = t & 63;
  int quad = lane >> 4, l16 = lane & 15;
  int wm = (wave >> 1) * 64, wn = (wave & 1) * 64;
  int gRow = b * L;
  #pragma unroll
  for (int fi = 0; fi < 4; ++fi)
    #pragma unroll
    for (int r = 0; r < 4; ++r) {
      int m = m0 + wm + fi * 16 + quad * 4 + r;
      int gi = gRow + m;
      float di = dinv[gi];
      float rm = mask ? mask[gi] : 1.f;
      #pragma unroll
      for (int fj = 0; fj < 4; ++fj) {
        int n = n0 + wn + fj * 16 + l16;
        float v = acc[fi][fj][r] * di + bias[n];
        if (encE) v += (float)encE[(size_t)gi * DG + n];
        v = fmaxf(v, 0.f);
        v *= rm;
        Y[(size_t)gi * DG + n] = (__bf16)v;
      }
    }
}

// ---------------------------------------------------------------------------
// fct merged: grid (8, 7, 18). bz<16: pro (b=bz, n over L); bz>=16: pep
// (n over BL flattened, b=n>>7). out f32.
// ---------------------------------------------------------------------------
__global__ __launch_bounds__(256) void fct_merged(
    const __bf16* __restrict__ WtBp, const float* __restrict__ btp,
    const __bf16* __restrict__ Yp, float* __restrict__ outP,
    const __bf16* __restrict__ WtBr, const float* __restrict__ btr,
    const __bf16* __restrict__ Yr, float* __restrict__ outR) {
  int kh = blockIdx.y;
  int pro = (blockIdx.z < 16);
  const __bf16* A;
  const ushort* B;
  const float* bt;
  int n0;
  if (pro) {
    A = WtBr + (size_t)kh * DD * DG;
    B = (const ushort*)(Yr + (size_t)blockIdx.z * LR * DG);
    bt = btr;
    n0 = blockIdx.x * 128;
  } else {
    A = WtBp + (size_t)kh * DD * DG;
    B = (const ushort*)Yp;
    bt = btp;
    n0 = ((blockIdx.z - 16) * 8 + blockIdx.x) * 128;
  }

  f32x4 acc[4][4];
  #pragma unroll
  for (int i = 0; i < 4; ++i)
    #pragma unroll
    for (int j = 0; j < 4; ++j) acc[i][j] = (f32x4){0.f, 0.f, 0.f, 0.f};
  mfma_core<0>(A, DG, B, DG, 0, n0, 0, DG, acc);

  int t = threadIdx.x;
  int wave = t >> 6, lane = t & 63;
  int quad = lane >> 4, l16 = lane & 15;
  int wm = (wave >> 1) * 64, wn = (wave & 1) * 64;
  #pragma unroll
  for (int fi = 0; fi < 4; ++fi)
    #pragma unroll
    for (int r = 0; r < 4; ++r) {
      int m = wm + fi * 16 + quad * 4 + r;
      float bb = bt[kh * DD + m];
      #pragma unroll
      for (int fj = 0; fj < 4; ++fj) {
        int n = n0 + wn + fj * 16 + l16;
        float v = fmaxf(acc[fi][fj][r] + bb, 0.f);
        if (pro) {
          outR[((size_t)(kh * BSZ + blockIdx.z) * DD + m) * LR + n] = v;
        } else {
          int b = n >> 7, l = n & 127;
          outP[((size_t)(kh * BSZ + b) * DD + m) * LP + l] = v;
        }
      }
    }
}

// ---------------------------------------------------------------------------
extern "C" void kernel_launch(void* const* d_in, const int* in_sizes, int n_in,
                              void* d_out, int out_size, void* d_ws, size_t ws_size,
                              hipStream_t stream) {
  const int*   x_pep          = (const int*)d_in[0];
  const int*   x_ss_pep       = (const int*)d_in[1];
  const int*   x_2_pep        = (const int*)d_in[2];
  const float* x_dense_pep    = (const float*)d_in[3];
  const float* x_pretrain_pep = (const float*)d_in[4];
  const int*   x_pro          = (const int*)d_in[5];
  const int*   x_ss_pro       = (const int*)d_in[6];
  const int*   x_2_pro        = (const int*)d_in[7];
  const float* x_dense_pro    = (const float*)d_in[8];
  const float* x_pretrain_pro = (const float*)d_in[9];
  const float* x_edge_pep     = (const float*)d_in[10];
  const float* x_edge_pro     = (const float*)d_in[11];
  const float* mask_pep       = (const float*)d_in[12];
  const float* mask_pro       = (const float*)d_in[13];
  const float* E_seq          = (const float*)d_in[14];
  const float* E_ss           = (const float*)d_in[15];
  const float* E_two          = (const float*)d_in[16];
  const float* W_dpep         = (const float*)d_in[17];
  const float* b_dpep         = (const float*)d_in[18];
  const float* W_dpro         = (const float*)d_in[19];
  const float* b_dpro         = (const float*)d_in[20];
  const float* W_ppep         = (const float*)d_in[21];
  const float* b_ppep         = (const float*)d_in[22];
  const float* W_ppro         = (const float*)d_in[23];
  const float* b_ppro         = (const float*)d_in[24];
  const float* Wg_pep1        = (const float*)d_in[25];
  const float* bg_pep1        = (const float*)d_in[26];
  const float* Wg_pep2        = (const float*)d_in[27];
  const float* bg_pep2        = (const float*)d_in[28];
  const float* Wg_pro1        = (const float*)d_in[29];
  const float* bg_pro1        = (const float*)d_in[30];
  const float* Wg_pro2        = (const float*)d_in[31];
  const float* bg_pro2        = (const float*)d_in[32];
  const float* Wt_pep         = (const float*)d_in[33];
  const float* bt_pep         = (const float*)d_in[34];
  const float* Wt_pro         = (const float*)d_in[35];
  const float* bt_pro         = (const float*)d_in[36];

  float* out = (float*)d_out;
  const int BLp = BSZ * LP;   // 2048
  const int BLr = BSZ * LR;   // 16384
  const size_t out_pro_off = (size_t)KH * BSZ * DD * LP;

  // Workspace layout (~117 MB)
  char* w = (char*)d_ws;
  __bf16* encBp  = (__bf16*)w; w += (size_t)BLp * DG * 2;
  __bf16* encBr  = (__bf16*)w; w += (size_t)BLr * DG * 2;
  __bf16* bufATp = (__bf16*)w; w += (size_t)DG * BLp * 2;
  __bf16* bufATr = (__bf16*)w; w += (size_t)DG * BLr * 2;
  __bf16* bufYp  = (__bf16*)w; w += (size_t)BLp * DG * 2;
  __bf16* bufYr  = (__bf16*)w; w += (size_t)BLr * DG * 2;
  __bf16* WppTp  = (__bf16*)w; w += (size_t)DD * 1024 * 2;
  __bf16* WppTr  = (__bf16*)w; w += (size_t)DD * 1024 * 2;
  __bf16* Wg1Tp  = (__bf16*)w; w += (size_t)DG * DG * 2;
  __bf16* Wg2Tp  = (__bf16*)w; w += (size_t)DG * DG * 2;
  __bf16* Wg1Tr  = (__bf16*)w; w += (size_t)DG * DG * 2;
  __bf16* Wg2Tr  = (__bf16*)w; w += (size_t)DG * DG * 2;
  __bf16* WtBp   = (__bf16*)w; w += (size_t)KH * DD * DG * 2;
  __bf16* WtBr   = (__bf16*)w; w += (size_t)KH * DD * DG * 2;
  uint32* packedP = (uint32*)w; w += (size_t)BSZ * (LP / 32) * LP * 4;
  uint32* packedR = (uint32*)w; w += (size_t)BSZ * (LR / 32) * LR * 4;
  float* degP  = (float*)w; w += (size_t)BLp * 4;
  float* degR  = (float*)w; w += (size_t)BLr * 4;
  float* dinvP = (float*)w; w += (size_t)BLp * 4;
  float* dinvR = (float*)w; w += (size_t)BLr * 4;
  float* partP = (float*)w; w += (size_t)SPLITK * BLp * DD * 4;
  float* partR = (float*)w; w += (size_t)SPLITK * BLr * DD * 4;

  // 1. weights
  prep_weights<<<dim3(560, 1, 8), 256, 0, stream>>>(
      W_ppep, W_ppro, Wg_pep1, Wg_pep2, Wg_pro1, Wg_pro2, Wt_pep, Wt_pro,
      WppTp, WppTr, Wg1Tp, Wg2Tp, Wg1Tr, Wg2Tr, WtBp, WtBr);
  // 2-4. adjacency prep
  zero_f32<<<(BLp + BLr) / 256, 256, 0, stream>>>(degP, BLp + BLr);
  prep_pack_merged<<<dim3(4, 32, 17), 256, 0, stream>>>(
      x_edge_pep, x_edge_pro, packedP, packedR, degP, degR);
  rsqrt_k<<<(BLp + BLr) / 256, 256, 0, stream>>>(degP, dinvP, BLp + BLr);
  // 5. pretrain split-K partials
  pre_gemm<<<dim3((BLp + BLr) / 128, SPLITK), 256, 0, stream>>>(
      x_pretrain_pep, x_pretrain_pro, WppTp, WppTr, partP, partR);
  // 6. encoder (+ pretrain reduce)
  encoder_merged<<<BLp + BLr, 128, 0, stream>>>(
      x_pep, x_ss_pep, x_2_pep, x_dense_pep, W_dpep, b_dpep, mask_pep, partP,
      b_ppep, encBp,
      x_pro, x_ss_pro, x_2_pro, x_dense_pro, W_dpro, b_dpro, mask_pro, partR,
      b_ppro, encBr,
      E_seq, E_ss, E_two);
  // 7-10. GCN
  linT_merged<<<dim3((BLp + BLr) / 128, DG / 128), 256, 0, stream>>>(
      Wg1Tp, encBp, dinvP, bufATp, Wg1Tr, encBr, dinvR, bufATr);
  agg_merged<<<dim3(80, 9), 256, 0, stream>>>(
      packedP, bufATp, dinvP, bg_pep1, nullptr, nullptr, bufYp,
      packedR, bufATr, dinvR, bg_pro1, nullptr, nullptr, bufYr);
  linT_merged<<<dim3((BLp + BLr) / 128, DG / 128), 256, 0, stream>>>(
      Wg2Tp, bufYp, dinvP, bufATp, Wg2Tr, bufYr, dinvR, bufATr);
  agg_merged<<<dim3(80, 9), 256, 0, stream>>>(
      packedP, bufATp, dinvP, bg_pep2, encBp, mask_pep, bufYp,
      packedR, bufATr, dinvR, bg_pro2, encBr, mask_pro, bufYr);
  // 11. fct
  fct_merged<<<dim3(LR / 128, KH, 18), 256, 0, stream>>>(
      WtBp, bt_pep, bufYp, out,
      WtBr, bt_pro, bufYr, out + out_pro_off);
}